// Round 1
// 1931.667 us; speedup vs baseline: 1.0440x; 1.0440x over previous
//
#include <hip/hip_runtime.h>

#define HW 65536            // 256*256

typedef __attribute__((ext_vector_type(8))) short bf16x8;
typedef __attribute__((ext_vector_type(4))) float floatx4;

__device__ inline void fma4(float4& a, float s, const float4& x){
    a.x = fmaf(s,x.x,a.x); a.y = fmaf(s,x.y,a.y);
    a.z = fmaf(s,x.z,a.z); a.w = fmaf(s,x.w,a.w);
}

__device__ inline unsigned short f2bf(float f){
    unsigned u = __builtin_bit_cast(unsigned, f);
    unsigned r = u + 0x7FFFu + ((u>>16)&1u);
    return (unsigned short)(r>>16);
}

// ============ weight prep: OIHW fp32 -> [conv][ch][tap][co][ci32] bf16 ========
__global__ void wprep_kernel(const float* __restrict__ w1, const float* __restrict__ w2,
                             unsigned short* __restrict__ wbf)
{
    int idx = blockIdx.x*256 + threadIdx.x;   // < 2*36864
    const float* src = (idx < 36864) ? w1 : w2;
    int l = idx % 36864;
    int ch = l / 18432;
    int r  = l % 18432;
    int tap = r >> 11;            // /2048
    int co  = (r >> 5) & 63;
    int ci  = r & 31;
    wbf[idx] = f2bf(src[co*576 + (ch*32+ci)*9 + tap]);
}

// ======== dense 3x3 conv 64->64 via bf16 MFMA, bias+relu (+res), fp32 io ======
// Block: 4 waves; tile = 64px (x) * 4 rows (y) * 64co.
// Grid: 4 xt * 64 yt * 4 b = 1024 blocks.
// Weights are read per-wave directly from global (L2-resident, 72KB total);
// LDS holds only the input tile [6 rows][66 xx][ci pad 72] in bf16.
__global__ __launch_bounds__(256,2)
void conv3x3_mfma_kernel(const float* __restrict__ in, const unsigned short* __restrict__ wbf,
                         const float* __restrict__ bias, const float* __restrict__ res,
                         float* __restrict__ out)
{
    __shared__ __align__(16) unsigned short s_in[6*66*72];   // 57024 B
    const int t = threadIdx.x;
    const int lane = t & 63, wv = t >> 6;
    const int n = lane & 15, q = lane >> 4;
    const int blk = blockIdx.x;
    const int xt = blk & 3, yt = (blk>>2) & 63, b = blk >> 8;
    const int x0 = xt*64, y0 = yt*4;

    const float* inb = in + (size_t)b*64*HW;

    // ---- stage 6 rows x 66 cols x 64 ci, fp32 -> bf16, layout [row][xx][ci] ----
    {
        // interior: xx = 1..64  (gx = x0..x0+63), fully coalesced, x always in-range
        const int xx1 = t & 63;
        int u = t >> 6;                    // composite ci/row, +4 per iter
        const float* gp = inb + x0 + xx1;
        #pragma unroll 4
        for (int i = 0; i < 96; i++) {
            int ci = u & 63, row = u >> 6;
            int gy = y0 + row - 1;
            float v = 0.f;
            if (gy >= 0 && gy < 256)
                v = gp[(size_t)ci*HW + gy*256];
            s_in[(row*66 + xx1 + 1)*72 + ci] = f2bf(v);
            u += 4;
        }
        // halo columns xx=0 (gx=x0-1) and xx=65 (gx=x0+64); mostly L2 hits
        for (int i = 0; i < 3; i++) {
            int idx = i*256 + t;           // < 768
            int ci = idx & 63;
            int side = (idx >> 6) & 1;
            int row = idx >> 7;
            int xx = side ? 65 : 0;
            int gx = x0 - 1 + side*65;
            int gy = y0 + row - 1;
            float v = 0.f;
            if (gx >= 0 && gx < 256 && gy >= 0 && gy < 256)
                v = inb[(size_t)ci*HW + gy*256 + gx];
            s_in[(row*66 + xx)*72 + ci] = f2bf(v);
        }
    }
    __syncthreads();

    floatx4 zero = {0.f,0.f,0.f,0.f};
    floatx4 acc[4][4];
    #pragma unroll
    for (int y=0;y<4;y++)
        #pragma unroll
        for (int s=0;s<4;s++) acc[y][s] = zero;

    for (int kk = 0; kk < 2; kk++) {
        // A-fragments (weights) straight from global: 9 x 16B per wave, L2-hot
        bf16x8 af[9];
        #pragma unroll
        for (int tap=0; tap<9; tap++)
            af[tap] = *(const bf16x8*)&wbf[kk*18432 + tap*2048 + (wv*16 + n)*32 + q*8];
        #pragma unroll
        for (int s=0;s<4;s++){
            #pragma unroll
            for (int dx=0;dx<3;dx++){
                // 6 row-fragments feed 12 MFMAs (ds_read:MFMA = 1:2)
                bf16x8 bf[6];
                #pragma unroll
                for (int r6=0;r6<6;r6++)
                    bf[r6] = *(const bf16x8*)&s_in[(r6*66 + s*16 + n + dx)*72 + kk*32 + q*8];
                #pragma unroll
                for (int dy=0;dy<3;dy++){
                    #pragma unroll
                    for (int y=0;y<4;y++)
                        acc[y][s] = __builtin_amdgcn_mfma_f32_16x16x32_bf16(
                            af[dy*3+dx], bf[y+dy], acc[y][s], 0,0,0);
                }
            }
        }
    }

    // epilogue: D col=lane&15 -> px, row=q*4+r -> co_local
    #pragma unroll
    for (int y=0;y<4;y++){
        #pragma unroll
        for (int s=0;s<4;s++){
            #pragma unroll
            for (int r=0;r<4;r++){
                int co = wv*16 + q*4 + r;
                int px = x0 + s*16 + n;
                size_t off = ((size_t)b*64+co)*HW + (size_t)(y0+y)*256 + px;
                float v = fmaxf(acc[y][s][r] + bias[co], 0.f);
                if (res) v += res[off];
                out[off] = v;
            }
        }
    }
}

// ======================= depthwise 3x3, pad 1, 4 px/thread =====================
__global__ __launch_bounds__(256,4)
void dw3x3_kernel(const float* __restrict__ in, int in_cs, int in_choff,
                  float* __restrict__ out, int out_cs, int out_choff,
                  const float* __restrict__ w, int w_choff,
                  const float* __restrict__ bias)
{
    const int c = blockIdx.x >> 6;
    const int p = ((blockIdx.x & 63) << 10) + threadIdx.x*4;
    const int x = p & 255, y = p >> 8;
    const int b = blockIdx.y;
    const float* ip = in + ((size_t)b*in_cs + in_choff + c)*HW;
    const float* wp = w + (size_t)(w_choff + c)*9;
    float row[3][6];
    #pragma unroll
    for (int dy=0; dy<3; dy++){
        int yy = y + dy - 1;
        if (yy < 0 || yy > 255){
            #pragma unroll
            for (int j=0;j<6;j++) row[dy][j]=0.f;
        } else {
            const float* rp = ip + yy*256;
            float4 m = *(const float4*)(rp + x);
            row[dy][1]=m.x; row[dy][2]=m.y; row[dy][3]=m.z; row[dy][4]=m.w;
            row[dy][0] = (x>0)   ? rp[x-1] : 0.f;
            row[dy][5] = (x<252) ? rp[x+4] : 0.f;
        }
    }
    float bv = bias ? bias[w_choff + c] : 0.f;
    float o[4] = {bv,bv,bv,bv};
    #pragma unroll
    for (int dy=0;dy<3;dy++){
        #pragma unroll
        for (int dx=0;dx<3;dx++){
            float wv = wp[dy*3+dx];
            #pragma unroll
            for (int i=0;i<4;i++) o[i] = fmaf(wv, row[dy][i+dx], o[i]);
        }
    }
    *(float4*)(out + ((size_t)b*out_cs + out_choff + c)*HW + p) =
        make_float4(o[0],o[1],o[2],o[3]);
}

// ======================= pointwise (1x1) conv v3 ==============================
template<int CIN, int COTILE>
__global__ __launch_bounds__(256,4)
void pw_kernel(const float* __restrict__ in, int in_cs, int in_choff,
               float* __restrict__ out, int out_cs, int out_choff,
               const float* __restrict__ w, int wbstride,
               const float* __restrict__ bias,
               const float* __restrict__ res, int relu_flag, int P)
{
    constexpr int Cpt = COTILE/4;
    __shared__ float s_w[CIN*COTILE];
    const int t = threadIdx.x;
    const int lane = t & 63, wv = t >> 6;
    const int b = blockIdx.y;
    const int co_base = blockIdx.z * COTILE;
    const int p0 = blockIdx.x * 256;
    const float* wb = w + (size_t)b*wbstride + (size_t)co_base*CIN;
    for (int idx = t; idx < CIN*COTILE; idx += 256) {
        int co = idx % COTILE, ci = idx / COTILE;
        s_w[ci*COTILE + co] = wb[(size_t)co*CIN + ci];
    }
    __syncthreads();
    const int wco = wv * Cpt;
    float4 acc[Cpt];
    #pragma unroll
    for (int c=0;c<Cpt;c++){
        float bv = bias ? bias[co_base + wco + c] : 0.f;
        acc[c] = make_float4(bv,bv,bv,bv);
    }
    const float* ip = in + ((size_t)b*in_cs + in_choff)*P + p0 + lane*4;
    for (int ci=0; ci<CIN; ci++) {
        float4 x = *(const float4*)(ip + (size_t)ci*P);
        const float4* wr = (const float4*)&s_w[ci*COTILE + wco];
        #pragma unroll
        for (int c4=0; c4<Cpt/4; c4++) {
            float4 ww = wr[c4];
            fma4(acc[c4*4+0], ww.x, x);
            fma4(acc[c4*4+1], ww.y, x);
            fma4(acc[c4*4+2], ww.z, x);
            fma4(acc[c4*4+3], ww.w, x);
        }
    }
    float* ob = out + ((size_t)b*out_cs + out_choff + co_base)*P + p0 + lane*4;
    const float* rb = res ? res + ((size_t)b*out_cs + out_choff + co_base)*P + p0 + lane*4
                          : nullptr;
    #pragma unroll
    for (int c=0;c<Cpt;c++){
        float4 v = acc[c];
        if (relu_flag){
            v.x=fmaxf(v.x,0.f); v.y=fmaxf(v.y,0.f);
            v.z=fmaxf(v.z,0.f); v.w=fmaxf(v.w,0.f);
        }
        if (rb){
            float4 r = *(const float4*)(rb + (size_t)(wco+c)*P);
            v.x+=r.x; v.y+=r.y; v.z+=r.z; v.w+=r.w;
        }
        *(float4*)(ob + (size_t)(wco+c)*P) = v;
    }
}

// ======================= FFT kernels ==========================================
// Main freq buffer pm: [b][128][32768], channel c<64 = Re(c), c>=64 = Im(c-64);
// pixel = h*128 + k for k=0..127.  Nyquist column pe: [b][128][256], index h.

__global__ __launch_bounds__(256,4)
void rfftw_kernel(const float* __restrict__ x, float* __restrict__ pm,
                  float* __restrict__ pe)
{
    __shared__ float sre[2*256], sim[2*256];
    const int t = threadIdx.x;
    const int r = t >> 7, lt = t & 127;
    const int row = blockIdx.x*2 + r;
    const int bc = row >> 8, h = row & 255;
    const float* xp = x + (size_t)bc*HW + h*256;
    float* base = sre + r*256; float* basei = sim + r*256;
    {
        int i1 = lt, i2 = lt + 128;
        int r1 = __brev((unsigned)i1) >> 24, r2 = __brev((unsigned)i2) >> 24;
        base[r1] = xp[i1]; basei[r1] = 0.f;
        base[r2] = xp[i2]; basei[r2] = 0.f;
    }
    __syncthreads();
    for (int s=1; s<=8; s++) {
        int m = 1<<s, half = m>>1;
        int j = lt & (half-1);
        int grp = lt >> (s-1);
        int i1 = grp*m + j, i2 = i1 + half;
        float ang = -6.283185307179586f * (float)j / (float)m;
        float sn, cs; __sincosf(ang, &sn, &cs);
        float ar = base[i1], ai = basei[i1];
        float br = base[i2], bi = basei[i2];
        float tr = cs*br - sn*bi, ti = cs*bi + sn*br;
        base[i1] = ar + tr; basei[i1] = ai + ti;
        base[i2] = ar - tr; basei[i2] = ai - ti;
        __syncthreads();
    }
    const int b = bc >> 6, c = bc & 63;
    float* pre = pm + ((size_t)b*128 + c)*32768 + h*128;
    float* pim = pm + ((size_t)b*128 + 64 + c)*32768 + h*128;
    pre[lt] = base[lt]; pim[lt] = basei[lt];
    if (lt == 0) {
        pe[((size_t)b*128 + c)*256 + h]      = base[128];
        pe[((size_t)b*128 + 64 + c)*256 + h] = basei[128];
    }
}

__global__ __launch_bounds__(256,2)
void ffth_kernel(float* __restrict__ pm, float* __restrict__ pe, int inverse)
{
    __shared__ float sre[256*16], sim[256*16];   // [h][col]
    const int t = threadIdx.x;
    const int blk = blockIdx.x;
    const int chunk = blk % 9;
    const int bc = blk / 9;
    const int b = bc >> 6, c = bc & 63;
    const int col = t & 15;
    const int hb = t >> 4;
    const bool edge = (chunk == 8);
    const bool valid = edge ? (col == 0) : true;
    const int k = chunk*16 + col;
    float* pre; float* pim; int hstride;
    if (edge) {
        pre = pe + ((size_t)b*128 + c)*256;
        pim = pe + ((size_t)b*128 + 64 + c)*256;
        hstride = 1;
    } else {
        pre = pm + ((size_t)b*128 + c)*32768 + k;
        pim = pm + ((size_t)b*128 + 64 + c)*32768 + k;
        hstride = 128;
    }
    for (int hh = 0; hh < 16; hh++) {
        int h = hh*16 + hb;
        float vr = 0.f, vi = 0.f;
        if (valid) { vr = pre[h*hstride]; vi = pim[h*hstride]; }
        sre[h*16+col] = vr; sim[h*16+col] = vi;
    }
    __syncthreads();
    if (!inverse) {
        for (int s=8; s>=1; s--) {
            int m = 1<<s, half = m>>1;
            for (int it=0; it<8; it++) {
                int task = it*256 + t;
                int cl = task & 15;
                int bf = task >> 4;
                int j = bf & (half-1);
                int grp = bf >> (s-1);
                int i1 = grp*m + j, i2 = i1 + half;
                float ang = -6.283185307179586f * (float)j / (float)m;
                float sn, cs; __sincosf(ang, &sn, &cs);
                float ar = sre[i1*16+cl], ai = sim[i1*16+cl];
                float br = sre[i2*16+cl], bi = sim[i2*16+cl];
                float dr = ar - br, di = ai - bi;
                sre[i1*16+cl] = ar + br; sim[i1*16+cl] = ai + bi;
                sre[i2*16+cl] = cs*dr - sn*di;
                sim[i2*16+cl] = cs*di + sn*dr;
            }
            __syncthreads();
        }
    } else {
        for (int s=1; s<=8; s++) {
            int m = 1<<s, half = m>>1;
            for (int it=0; it<8; it++) {
                int task = it*256 + t;
                int cl = task & 15;
                int bf = task >> 4;
                int j = bf & (half-1);
                int grp = bf >> (s-1);
                int i1 = grp*m + j, i2 = i1 + half;
                float ang = 6.283185307179586f * (float)j / (float)m;
                float sn, cs; __sincosf(ang, &sn, &cs);
                float ar = sre[i1*16+cl], ai = sim[i1*16+cl];
                float br = sre[i2*16+cl], bi = sim[i2*16+cl];
                float tr = cs*br - sn*bi, ti = cs*bi + sn*br;
                sre[i1*16+cl] = ar + tr; sim[i1*16+cl] = ai + ti;
                sre[i2*16+cl] = ar - tr; sim[i2*16+cl] = ai - ti;
            }
            __syncthreads();
        }
    }
    const float scale = inverse ? (1.0f/256.0f) : 1.0f;
    for (int hh = 0; hh < 16; hh++) {
        int h = hh*16 + hb;
        if (valid) {
            pre[h*hstride] = sre[h*16+col]*scale;
            pim[h*hstride] = sim[h*16+col]*scale;
        }
    }
}

__global__ __launch_bounds__(256,4)
void irfftw_kernel(const float* __restrict__ pm, const float* __restrict__ pe,
                   float* __restrict__ outp)
{
    __shared__ float sre[2*256], sim[2*256];
    const int t = threadIdx.x;
    const int r = t >> 7, lt = t & 127;
    const int row = blockIdx.x*2 + r;
    const int bc = row >> 8, h = row & 255;
    const int b = bc >> 6, c = bc & 63;
    const float* pre = pm + ((size_t)b*128 + c)*32768 + h*128;
    const float* pim = pm + ((size_t)b*128 + 64 + c)*32768 + h*128;
    float* base = sre + r*256; float* basei = sim + r*256;
    {
        float xr = pre[lt], xi = pim[lt];
        int d1 = __brev((unsigned)lt) >> 24;
        base[d1] = xr; basei[d1] = xi;
        int k2 = lt + 128;
        int d2 = __brev((unsigned)k2) >> 24;
        float yr, yi;
        if (lt == 0) {
            yr = pe[((size_t)b*128 + c)*256 + h];
            yi = pe[((size_t)b*128 + 64 + c)*256 + h];
        } else {
            yr = pre[128-lt]; yi = -pim[128-lt];
        }
        base[d2] = yr; basei[d2] = yi;
    }
    __syncthreads();
    for (int s=1; s<=8; s++) {
        int m = 1<<s, half = m>>1;
        int j = lt & (half-1);
        int grp = lt >> (s-1);
        int i1 = grp*m + j, i2 = i1 + half;
        float ang = 6.283185307179586f * (float)j / (float)m;
        float sn, cs; __sincosf(ang, &sn, &cs);
        float ar = base[i1], ai = basei[i1];
        float br = base[i2], bi = basei[i2];
        float tr = cs*br - sn*bi, ti = cs*bi + sn*br;
        base[i1] = ar + tr; basei[i1] = ai + ti;
        base[i2] = ar - tr; basei[i2] = ai - ti;
        __syncthreads();
    }
    float* op = outp + (size_t)bc*HW + h*256;
    op[lt]     = base[lt]     * (1.0f/256.0f);
    op[lt+128] = base[lt+128] * (1.0f/256.0f);
}

// ======================= attention gram reduction (4 heads / launch) ==========
__global__ __launch_bounds__(256,2)
void gram4_kernel(const float* __restrict__ q, int q_cs, int q_choff,
                  const float* __restrict__ k, int k_cs, int k_choff,
                  int head_base,
                  float* __restrict__ G, float* __restrict__ qq, float* __restrict__ kk)
{
    const int blk = blockIdx.x;
    const int chunk = blk & 63;
    const int bhl = blk >> 6;        // 0..15
    const int b = bhl >> 2, lh = bhl & 3;
    const int g = head_base + lh;
    const int t = threadIdx.x;
    const int p0 = chunk * 1024;
    const float* qb = q + ((size_t)b*q_cs + q_choff + lh*8)*HW;
    const float* kb = k + ((size_t)b*k_cs + k_choff + lh*8)*HW;
    float gm[8][8], sq[8], sk[8];
    #pragma unroll
    for (int c=0;c<8;c++){ sq[c]=0.f; sk[c]=0.f;
        #pragma unroll
        for (int d=0;d<8;d++) gm[c][d]=0.f; }
    for (int i=0;i<4;i++) {
        const int p = p0 + i*256 + t;
        float qa[8], ka[8];
        #pragma unroll
        for (int c=0;c<8;c++){ qa[c]=qb[(size_t)c*HW+p]; ka[c]=kb[(size_t)c*HW+p]; }
        #pragma unroll
        for (int c=0;c<8;c++) {
            sq[c]=fmaf(qa[c],qa[c],sq[c]);
            sk[c]=fmaf(ka[c],ka[c],sk[c]);
            #pragma unroll
            for (int d=0;d<8;d++) gm[c][d]=fmaf(qa[c],ka[d],gm[c][d]);
        }
    }
    __shared__ float red[4][88];
    const int wv = t >> 6, ln = t & 63;
    #pragma unroll
    for (int c=0;c<8;c++){
        #pragma unroll
        for (int d=0;d<8;d++){
            float v = gm[c][d];
            #pragma unroll
            for (int off=32; off>=1; off>>=1) v += __shfl_down(v, off);
            if (ln==0) red[wv][c*8+d] = v;
        }
    }
    #pragma unroll
    for (int c=0;c<8;c++){
        float v = sq[c];
        #pragma unroll
        for (int off=32; off>=1; off>>=1) v += __shfl_down(v, off);
        if (ln==0) red[wv][64+c] = v;
        float u = sk[c];
        #pragma unroll
        for (int off=32; off>=1; off>>=1) u += __shfl_down(u, off);
        if (ln==0) red[wv][72+c] = u;
    }
    __syncthreads();
    if (t < 80) {
        float s = red[0][t] + red[1][t] + red[2][t] + red[3][t];
        const size_t bh = (size_t)b*8 + g;
        if (t < 64)      atomicAdd(&G[bh*64 + t], s);
        else if (t < 72) atomicAdd(&qq[bh*8 + (t-64)], s);
        else             atomicAdd(&kk[bh*8 + (t-72)], s);
    }
}

// ======================= softmax + fold proj into per-batch M =================
__global__ void attnmat_kernel(const float* __restrict__ G, const float* __restrict__ qq,
                               const float* __restrict__ kk, const float* __restrict__ temp,
                               const float* __restrict__ projw, float* __restrict__ M)
{
    __shared__ float A[2048];   // [bh][c][d]
    const int t = threadIdx.x;
    for (int i = t; i < 2048; i += 256) {
        int d = i & 7, c = (i>>3)&7, bh = i>>6;
        int h = bh & 7;
        float nq = fmaxf(sqrtf(qq[bh*8+c]), 1e-12f);
        float nk = fmaxf(sqrtf(kk[bh*8+d]), 1e-12f);
        A[i] = G[i] / (nq*nk) * temp[h];
    }
    __syncthreads();
    {
        int base = t*8;
        float mx = -1e30f;
        #pragma unroll
        for (int d=0;d<8;d++) mx = fmaxf(mx, A[base+d]);
        float e[8]; float sum = 0.f;
        #pragma unroll
        for (int d=0;d<8;d++){ e[d] = __expf(A[base+d]-mx); sum += e[d]; }
        float inv = 1.0f/sum;
        #pragma unroll
        for (int d=0;d<8;d++) A[base+d] = e[d]*inv;
    }
    __syncthreads();
    for (int i=t; i<16384; i+=256) {
        int hd = i & 63, co = (i>>6)&63, b = i>>12;
        int h = hd>>3, d = hd&7;
        float s = 0.f;
        #pragma unroll
        for (int c=0;c<8;c++)
            s = fmaf(projw[co*64 + h*8 + c], A[((b*8+h)*8+c)*8 + d], s);
        M[i] = s;
    }
}

// ======================= final: pw(64->128)+bias+sigmoid, gate, nan_to_num ====
__global__ __launch_bounds__(256,4)
void fuse_final_kernel(const float* __restrict__ t2, int t2_cs, int t2_choff,
                       const float* __restrict__ w, const float* __restrict__ bias,
                       const float* __restrict__ fre, const float* __restrict__ spa,
                       float* __restrict__ outp)
{
    __shared__ float s_w[64*128];   // [ci][co], co in 0..127 (32 KB)
    const int t = threadIdx.x, lane = t & 63, wv = t >> 6;
    const int b = blockIdx.y;
    const int p0 = blockIdx.x * 128;
    for (int idx=t; idx<8192; idx+=256){
        int co = idx & 127, ci = idx >> 7;
        s_w[ci*128 + co] = w[(size_t)co*64 + ci];
    }
    __syncthreads();
    const int wco = wv*16;
    float2 a1[16], a2[16];
    #pragma unroll
    for (int c=0;c<16;c++){
        float b1 = bias[wco+c], b2 = bias[64+wco+c];
        a1[c] = make_float2(b1,b1); a2[c] = make_float2(b2,b2);
    }
    const float* ip = t2 + ((size_t)b*t2_cs + t2_choff)*HW + p0 + lane*2;
    for (int ci=0; ci<64; ci++){
        float2 x = *(const float2*)(ip + (size_t)ci*HW);
        const float4* w1 = (const float4*)&s_w[ci*128 + wco];
        const float4* w2 = (const float4*)&s_w[ci*128 + 64 + wco];
        #pragma unroll
        for (int c4=0;c4<4;c4++){
            float4 u = w1[c4], v = w2[c4];
            a1[c4*4+0].x = fmaf(u.x,x.x,a1[c4*4+0].x); a1[c4*4+0].y = fmaf(u.x,x.y,a1[c4*4+0].y);
            a1[c4*4+1].x = fmaf(u.y,x.x,a1[c4*4+1].x); a1[c4*4+1].y = fmaf(u.y,x.y,a1[c4*4+1].y);
            a1[c4*4+2].x = fmaf(u.z,x.x,a1[c4*4+2].x); a1[c4*4+2].y = fmaf(u.z,x.y,a1[c4*4+2].y);
            a1[c4*4+3].x = fmaf(u.w,x.x,a1[c4*4+3].x); a1[c4*4+3].y = fmaf(u.w,x.y,a1[c4*4+3].y);
            a2[c4*4+0].x = fmaf(v.x,x.x,a2[c4*4+0].x); a2[c4*4+0].y = fmaf(v.x,x.y,a2[c4*4+0].y);
            a2[c4*4+1].x = fmaf(v.y,x.x,a2[c4*4+1].x); a2[c4*4+1].y = fmaf(v.y,x.y,a2[c4*4+1].y);
            a2[c4*4+2].x = fmaf(v.z,x.x,a2[c4*4+2].x); a2[c4*4+2].y = fmaf(v.z,x.y,a2[c4*4+2].y);
            a2[c4*4+3].x = fmaf(v.w,x.x,a2[c4*4+3].x); a2[c4*4+3].y = fmaf(v.w,x.y,a2[c4*4+3].y);
        }
    }
    #pragma unroll
    for (int c=0;c<16;c++){
        int co = wco + c;
        float s1x = 1.0f/(1.0f+__expf(-a1[c].x)), s1y = 1.0f/(1.0f+__expf(-a1[c].y));
        float s2x = 1.0f/(1.0f+__expf(-a2[c].x)), s2y = 1.0f/(1.0f+__expf(-a2[c].y));
        size_t off = ((size_t)b*64 + co)*HW + p0 + lane*2;
        float2 f = *(const float2*)(fre + off);
        float2 s = *(const float2*)(spa + off);
        float rx = f.x*s1x + s2x*s.x;
        float ry = f.y*s1y + s2y*s.y;
        if (!__builtin_isfinite(rx)) rx = 1e-5f;
        if (!__builtin_isfinite(ry)) ry = 1e-5f;
        *(float2*)(outp + off) = make_float2(rx, ry);
    }
}

// =============================== launcher =====================================
extern "C" void kernel_launch(void* const* d_in, const int* in_sizes, int n_in,
                              void* d_out, int out_size, void* d_ws, size_t ws_size,
                              hipStream_t stream) {
    const float* x0      = (const float*)d_in[0];
    const float* x1      = (const float*)d_in[1];
    const float* rl_w1   = (const float*)d_in[2];
    const float* rl_b1   = (const float*)d_in[3];
    const float* rl_w2   = (const float*)d_in[4];
    const float* rl_b2   = (const float*)d_in[5];
    const float* rg_w1   = (const float*)d_in[6];
    const float* rg_w2   = (const float*)d_in[7];
    const float* att_temp= (const float*)d_in[8];
    const float* kv_w    = (const float*)d_in[9];
    const float* kv_dw   = (const float*)d_in[10];
    const float* q_w     = (const float*)d_in[11];
    const float* q_dw    = (const float*)d_in[12];
    const float* proj_w  = (const float*)d_in[13];
    const float* f1_dw   = (const float*)d_in[14];
    const float* f1_dwb  = (const float*)d_in[15];
    const float* f1_pw   = (const float*)d_in[16];
    const float* f1_pwb  = (const float*)d_in[17];
    const float* f2_dw   = (const float*)d_in[18];
    const float* f2_dwb  = (const float*)d_in[19];
    const float* f2_pw   = (const float*)d_in[20];
    const float* f2_pwb  = (const float*)d_in[21];
    float* out = (float*)d_out;
    float* ws  = (float*)d_ws;

    const size_t A = (size_t)4*64*HW;       // 16,777,216 floats (64 MB)
    float* R0   = ws;                        // scratch A (freq main buffer)
    float* R1   = ws + A;                    // scratch A
    float* spa  = ws + 2*A;                  // persistent A
    float* PFe  = ws + 3*A;                  // Nyquist col: 4*128*256 = 131072
    float* PFe2 = PFe + 131072;              // Nyquist scratch
    float* G    = PFe2 + 131072;             // 2048
    float* qqv  = G + 2048;                  // 256
    float* kkv  = qqv + 256;                 // 256
    float* M    = kkv + 256;                 // 16384
    unsigned short* wbf = (unsigned short*)(M + 16384);  // 2*36864 bf16
    float* fre  = out;                       // fre lives in d_out

    const dim3 g_pw_hw(256, 4, 1);           // pw over HW, COTILE==COUT
    const dim3 g_pw_fq(128, 4, 2);           // freq main, COUT=128 split in 2
    const dim3 g_pw_fe(1, 4, 2);             // freq edge
    const dim3 dwg64(64*64, 4);
    const dim3 dwg32(32*64, 4);

    // ---------- weight prep for MFMA convs ----------
    wprep_kernel<<<288,256,0,stream>>>(rl_w1, rl_w2, wbf);

    // ---------- Stage 1: ResBlock_L -> fre (in d_out) ----------
    conv3x3_mfma_kernel<<<1024,256,0,stream>>>(x0, wbf,         rl_b1, nullptr, R0);
    conv3x3_mfma_kernel<<<1024,256,0,stream>>>(R0, wbf + 36864, rl_b2, x0,      fre);

    // ---------- Stage 2: ResBlock_G -> spa ----------
    rfftw_kernel<<<32768,256,0,stream>>>(x1, R0, PFe);
    ffth_kernel<<<2304,256,0,stream>>>(R0, PFe, 0);
    pw_kernel<128,64><<<g_pw_fq,256,0,stream>>>(R0,128,0,  R1,128,0,  rg_w1,0, nullptr, nullptr, 1, 32768);
    pw_kernel<128,64><<<g_pw_fe,256,0,stream>>>(PFe,128,0, PFe2,128,0, rg_w1,0, nullptr, nullptr, 1, 256);
    pw_kernel<128,64><<<g_pw_fq,256,0,stream>>>(R1,128,0,  R0,128,0,  rg_w2,0, nullptr, nullptr, 0, 32768);
    pw_kernel<128,64><<<g_pw_fe,256,0,stream>>>(PFe2,128,0, PFe,128,0, rg_w2,0, nullptr, nullptr, 0, 256);
    ffth_kernel<<<2304,256,0,stream>>>(R0, PFe, 1);
    irfftw_kernel<<<32768,256,0,stream>>>(R0, PFe, spa);

    // ---------- attention (shared weights), applied twice ----------
    auto attention = [&](const float* xq, const float* ykv, float* io) {
        hipMemsetAsync(G, 0, 2560*sizeof(float), stream);
        for (int hh = 0; hh < 2; hh++) {
            const int cb = hh*32;
            // k32 = dw(pw(ykv, kv_w rows cb..cb+31))
            pw_kernel<64,32><<<g_pw_hw,256,0,stream>>>(ykv,64,0, R0,32,0, kv_w + (size_t)cb*64, 0, nullptr, nullptr, 0, HW);
            dw3x3_kernel<<<dwg32,256,0,stream>>>(R0,32,0, R1,64,0,  kv_dw, cb, nullptr);
            // q32 = dw(pw(xq, q_w rows cb..cb+31))
            pw_kernel<64,32><<<g_pw_hw,256,0,stream>>>(xq,64,0,  R0,32,0, q_w + (size_t)cb*64, 0, nullptr, nullptr, 0, HW);
            dw3x3_kernel<<<dwg32,256,0,stream>>>(R0,32,0, R1,64,32, q_dw, cb, nullptr);
            gram4_kernel<<<1024,256,0,stream>>>(R1,64,32, R1,64,0, hh*4, G, qqv, kkv);
        }
        attnmat_kernel<<<1,256,0,stream>>>(G, qqv, kkv, att_temp, proj_w, M);
        // v = dw(pw(ykv, kv_w rows 64..127))
        pw_kernel<64,64><<<g_pw_hw,256,0,stream>>>(ykv,64,0, R0,64,0, kv_w + (size_t)64*64, 0, nullptr, nullptr, 0, HW);
        dw3x3_kernel<<<dwg64,256,0,stream>>>(R0,64,0, R1,64,0, kv_dw, 64, nullptr);
        // io = M_b * v + io   (proj folded into M; in-place residual safe)
        pw_kernel<64,64><<<g_pw_hw,256,0,stream>>>(R1,64,0, io,64,0, M, 4096, nullptr, io, 0, HW);
    };
    attention(fre, spa, fre);   // fre = att(fre, spa) + fre
    attention(spa, fre, spa);   // spa = att(spa, fre_new) + spa

    // ---------- Stage 5: fuse (R0..R1 as one [b][128][HW] buffer) -------------
    float* W128 = R0;
    dw3x3_kernel<<<dwg64,256,0,stream>>>(fre,64,0, W128,128,0,  f1_dw, 0,  f1_dwb);
    dw3x3_kernel<<<dwg64,256,0,stream>>>(spa,64,0, W128,128,64, f1_dw, 64, f1_dwb);
    // pw 128->64 +bias, in-place into ch0..63 of W128 (z==1, block-local tiles)
    pw_kernel<128,64><<<g_pw_hw,256,0,stream>>>(W128,128,0, W128,128,0, f1_pw,0, f1_pwb, nullptr, 0, HW);
    // dw3x3 64ch +bias: read ch0..63, write ch64..127 (disjoint)
    dw3x3_kernel<<<dwg64,256,0,stream>>>(W128,128,0, W128,128,64, f2_dw, 0, f2_dwb);
    // pw 64->128 +bias, sigmoid, gate, nan_to_num -> out (in-place with fre)
    fuse_final_kernel<<<dim3(512,4),256,0,stream>>>(W128,128,64, f2_pw, f2_pwb, fre, spa, out);
    (void)in_sizes; (void)n_in; (void)out_size; (void)ws_size;
}

// Round 2
// 1804.089 us; speedup vs baseline: 1.1178x; 1.0707x over previous
//
#include <hip/hip_runtime.h>

#define HW 65536            // 256*256

typedef __attribute__((ext_vector_type(8))) short bf16x8;
typedef __attribute__((ext_vector_type(4))) float floatx4;

__device__ inline void fma4(float4& a, float s, const float4& x){
    a.x = fmaf(s,x.x,a.x); a.y = fmaf(s,x.y,a.y);
    a.z = fmaf(s,x.z,a.z); a.w = fmaf(s,x.w,a.w);
}

__device__ inline unsigned short f2bf(float f){
    unsigned u = __builtin_bit_cast(unsigned, f);
    unsigned r = u + 0x7FFFu + ((u>>16)&1u);
    return (unsigned short)(r>>16);
}

// ============ weight prep: OIHW fp32 -> [conv][ch][tap][co][ci32] bf16 ========
__global__ void wprep_kernel(const float* __restrict__ w1, const float* __restrict__ w2,
                             unsigned short* __restrict__ wbf)
{
    int idx = blockIdx.x*256 + threadIdx.x;   // < 2*36864
    const float* src = (idx < 36864) ? w1 : w2;
    int l = idx % 36864;
    int ch = l / 18432;
    int r  = l % 18432;
    int tap = r >> 11;            // /2048
    int co  = (r >> 5) & 63;
    int ci  = r & 31;
    wbf[idx] = f2bf(src[co*576 + (ch*32+ci)*9 + tap]);
}

// ======== dense 3x3 conv 64->64 via bf16 MFMA, bias+relu (+res), fp32 io ======
// Block: 4 waves; tile = 64px (x) * 4 rows (y) * 64co.
// Grid: 4 xt * 64 yt * 4 b = 1024 blocks.
// Weights are read per-wave directly from global (L2-resident, 72KB total);
// LDS holds only the input tile [6 rows][66 xx][ci pad 72] in bf16.
// Staging: float4 loads batched 12-deep in registers for memory-level parallelism.
__global__ __launch_bounds__(256,2)
void conv3x3_mfma_kernel(const float* __restrict__ in, const unsigned short* __restrict__ wbf,
                         const float* __restrict__ bias, const float* __restrict__ res,
                         float* __restrict__ out)
{
    __shared__ __align__(16) unsigned short s_in[6*66*72];   // 57024 B
    const int t = threadIdx.x;
    const int lane = t & 63, wv = t >> 6;
    const int n = lane & 15, q = lane >> 4;
    const int blk = blockIdx.x;
    const int xt = blk & 3, yt = (blk>>2) & 63, b = blk >> 8;
    const int x0 = xt*64, y0 = yt*4;

    const float* inb = in + (size_t)b*64*HW;

    // ---- stage 6 rows x 66 cols x 64 ci, fp32 -> bf16, layout [row][xx][ci] ----
    {
        // interior: xx = 1..64 (gx = x0..x0+63); thread handles one float4 (4 px)
        // per (row,ci); 24 float4/thread in 2 register-batched chunks of 12.
        const int xq = t & 15;             // x-group of 4
        const int u0 = t >> 4;             // 0..15, composite ci/row base
        const float* gp0 = inb + x0 + xq*4;
        float4 tmp[12];
        #pragma unroll
        for (int ch = 0; ch < 2; ch++) {
            #pragma unroll
            for (int i = 0; i < 12; i++) {
                int u = u0 + (ch*12 + i)*16;     // 0..383
                int ci = u & 63, row = u >> 6;
                int gy = y0 + row - 1;
                float4 v = make_float4(0.f,0.f,0.f,0.f);
                if (gy >= 0 && gy < 256)
                    v = *(const float4*)(gp0 + (size_t)ci*HW + (size_t)gy*256);
                tmp[i] = v;
            }
            #pragma unroll
            for (int i = 0; i < 12; i++) {
                int u = u0 + (ch*12 + i)*16;
                int ci = u & 63, row = u >> 6;
                unsigned short* d = &s_in[(row*66 + xq*4 + 1)*72 + ci];
                d[0]   = f2bf(tmp[i].x);
                d[72]  = f2bf(tmp[i].y);
                d[144] = f2bf(tmp[i].z);
                d[216] = f2bf(tmp[i].w);
            }
        }
        // halo columns xx=0 (gx=x0-1) and xx=65 (gx=x0+64); mostly L2 hits
        float hv[3];
        #pragma unroll
        for (int i = 0; i < 3; i++) {
            int idx = i*256 + t;           // < 768
            int ci = idx & 63;
            int side = (idx >> 6) & 1;
            int row = idx >> 7;
            int gx = x0 - 1 + side*65;
            int gy = y0 + row - 1;
            float v = 0.f;
            if (gx >= 0 && gx < 256 && gy >= 0 && gy < 256)
                v = inb[(size_t)ci*HW + (size_t)gy*256 + gx];
            hv[i] = v;
        }
        #pragma unroll
        for (int i = 0; i < 3; i++) {
            int idx = i*256 + t;
            int ci = idx & 63;
            int side = (idx >> 6) & 1;
            int row = idx >> 7;
            int xx = side ? 65 : 0;
            s_in[(row*66 + xx)*72 + ci] = f2bf(hv[i]);
        }
    }
    __syncthreads();

    floatx4 zero = {0.f,0.f,0.f,0.f};
    floatx4 acc[4][4];
    #pragma unroll
    for (int y=0;y<4;y++)
        #pragma unroll
        for (int s=0;s<4;s++) acc[y][s] = zero;

    for (int kk = 0; kk < 2; kk++) {
        // A-fragments (weights) straight from global: 9 x 16B per wave, L2-hot
        bf16x8 af[9];
        #pragma unroll
        for (int tap=0; tap<9; tap++)
            af[tap] = *(const bf16x8*)&wbf[kk*18432 + tap*2048 + (wv*16 + n)*32 + q*8];
        #pragma unroll
        for (int s=0;s<4;s++){
            #pragma unroll
            for (int dx=0;dx<3;dx++){
                // 6 row-fragments feed 12 MFMAs (ds_read:MFMA = 1:2)
                bf16x8 bf[6];
                #pragma unroll
                for (int r6=0;r6<6;r6++)
                    bf[r6] = *(const bf16x8*)&s_in[(r6*66 + s*16 + n + dx)*72 + kk*32 + q*8];
                #pragma unroll
                for (int dy=0;dy<3;dy++){
                    #pragma unroll
                    for (int y=0;y<4;y++)
                        acc[y][s] = __builtin_amdgcn_mfma_f32_16x16x32_bf16(
                            af[dy*3+dx], bf[y+dy], acc[y][s], 0,0,0);
                }
            }
        }
    }

    // epilogue: D col=lane&15 -> px, row=q*4+r -> co_local
    #pragma unroll
    for (int y=0;y<4;y++){
        #pragma unroll
        for (int s=0;s<4;s++){
            #pragma unroll
            for (int r=0;r<4;r++){
                int co = wv*16 + q*4 + r;
                int px = x0 + s*16 + n;
                size_t off = ((size_t)b*64+co)*HW + (size_t)(y0+y)*256 + px;
                float v = fmaxf(acc[y][s][r] + bias[co], 0.f);
                if (res) v += res[off];
                out[off] = v;
            }
        }
    }
}

// ======================= depthwise 3x3, pad 1, 4 px/thread =====================
__global__ __launch_bounds__(256,4)
void dw3x3_kernel(const float* __restrict__ in, int in_cs, int in_choff,
                  float* __restrict__ out, int out_cs, int out_choff,
                  const float* __restrict__ w, int w_choff,
                  const float* __restrict__ bias)
{
    const int c = blockIdx.x >> 6;
    const int p = ((blockIdx.x & 63) << 10) + threadIdx.x*4;
    const int x = p & 255, y = p >> 8;
    const int b = blockIdx.y;
    const float* ip = in + ((size_t)b*in_cs + in_choff + c)*HW;
    const float* wp = w + (size_t)(w_choff + c)*9;
    float row[3][6];
    #pragma unroll
    for (int dy=0; dy<3; dy++){
        int yy = y + dy - 1;
        if (yy < 0 || yy > 255){
            #pragma unroll
            for (int j=0;j<6;j++) row[dy][j]=0.f;
        } else {
            const float* rp = ip + yy*256;
            float4 m = *(const float4*)(rp + x);
            row[dy][1]=m.x; row[dy][2]=m.y; row[dy][3]=m.z; row[dy][4]=m.w;
            row[dy][0] = (x>0)   ? rp[x-1] : 0.f;
            row[dy][5] = (x<252) ? rp[x+4] : 0.f;
        }
    }
    float bv = bias ? bias[w_choff + c] : 0.f;
    float o[4] = {bv,bv,bv,bv};
    #pragma unroll
    for (int dy=0;dy<3;dy++){
        #pragma unroll
        for (int dx=0;dx<3;dx++){
            float wv = wp[dy*3+dx];
            #pragma unroll
            for (int i=0;i<4;i++) o[i] = fmaf(wv, row[dy][i+dx], o[i]);
        }
    }
    *(float4*)(out + ((size_t)b*out_cs + out_choff + c)*HW + p) =
        make_float4(o[0],o[1],o[2],o[3]);
}

// ======================= pointwise (1x1) conv v3 ==============================
template<int CIN, int COTILE>
__global__ __launch_bounds__(256, (COTILE >= 128 ? 2 : 4))
void pw_kernel(const float* __restrict__ in, int in_cs, int in_choff,
               float* __restrict__ out, int out_cs, int out_choff,
               const float* __restrict__ w, int wbstride,
               const float* __restrict__ bias,
               const float* __restrict__ res, int relu_flag, int P)
{
    constexpr int Cpt = COTILE/4;
    __shared__ float s_w[CIN*COTILE];
    const int t = threadIdx.x;
    const int lane = t & 63, wv = t >> 6;
    const int b = blockIdx.y;
    const int co_base = blockIdx.z * COTILE;
    const int p0 = blockIdx.x * 256;
    const float* wb = w + (size_t)b*wbstride + (size_t)co_base*CIN;
    for (int idx = t; idx < CIN*COTILE; idx += 256) {
        int co = idx % COTILE, ci = idx / COTILE;
        s_w[ci*COTILE + co] = wb[(size_t)co*CIN + ci];
    }
    __syncthreads();
    const int wco = wv * Cpt;
    float4 acc[Cpt];
    #pragma unroll
    for (int c=0;c<Cpt;c++){
        float bv = bias ? bias[co_base + wco + c] : 0.f;
        acc[c] = make_float4(bv,bv,bv,bv);
    }
    const float* ip = in + ((size_t)b*in_cs + in_choff)*P + p0 + lane*4;
    for (int ci=0; ci<CIN; ci++) {
        float4 x = *(const float4*)(ip + (size_t)ci*P);
        const float4* wr = (const float4*)&s_w[ci*COTILE + wco];
        #pragma unroll
        for (int c4=0; c4<Cpt/4; c4++) {
            float4 ww = wr[c4];
            fma4(acc[c4*4+0], ww.x, x);
            fma4(acc[c4*4+1], ww.y, x);
            fma4(acc[c4*4+2], ww.z, x);
            fma4(acc[c4*4+3], ww.w, x);
        }
    }
    float* ob = out + ((size_t)b*out_cs + out_choff + co_base)*P + p0 + lane*4;
    const float* rb = res ? res + ((size_t)b*out_cs + out_choff + co_base)*P + p0 + lane*4
                          : nullptr;
    #pragma unroll
    for (int c=0;c<Cpt;c++){
        float4 v = acc[c];
        if (relu_flag){
            v.x=fmaxf(v.x,0.f); v.y=fmaxf(v.y,0.f);
            v.z=fmaxf(v.z,0.f); v.w=fmaxf(v.w,0.f);
        }
        if (rb){
            float4 r = *(const float4*)(rb + (size_t)(wco+c)*P);
            v.x+=r.x; v.y+=r.y; v.z+=r.z; v.w+=r.w;
        }
        *(float4*)(ob + (size_t)(wco+c)*P) = v;
    }
}

// ======================= FFT kernels ==========================================
// Main freq buffer pm: [b][128][32768], channel c<64 = Re(c), c>=64 = Im(c-64);
// pixel = h*128 + k for k=0..127.  Nyquist column pe: [b][128][256], index h.

__global__ __launch_bounds__(256,4)
void rfftw_kernel(const float* __restrict__ x, float* __restrict__ pm,
                  float* __restrict__ pe)
{
    __shared__ float sre[2*256], sim[2*256];
    const int t = threadIdx.x;
    const int r = t >> 7, lt = t & 127;
    const int row = blockIdx.x*2 + r;
    const int bc = row >> 8, h = row & 255;
    const float* xp = x + (size_t)bc*HW + h*256;
    float* base = sre + r*256; float* basei = sim + r*256;
    {
        int i1 = lt, i2 = lt + 128;
        int r1 = __brev((unsigned)i1) >> 24, r2 = __brev((unsigned)i2) >> 24;
        base[r1] = xp[i1]; basei[r1] = 0.f;
        base[r2] = xp[i2]; basei[r2] = 0.f;
    }
    __syncthreads();
    for (int s=1; s<=8; s++) {
        int m = 1<<s, half = m>>1;
        int j = lt & (half-1);
        int grp = lt >> (s-1);
        int i1 = grp*m + j, i2 = i1 + half;
        float ang = -6.283185307179586f * (float)j / (float)m;
        float sn, cs; __sincosf(ang, &sn, &cs);
        float ar = base[i1], ai = basei[i1];
        float br = base[i2], bi = basei[i2];
        float tr = cs*br - sn*bi, ti = cs*bi + sn*br;
        base[i1] = ar + tr; basei[i1] = ai + ti;
        base[i2] = ar - tr; basei[i2] = ai - ti;
        __syncthreads();
    }
    const int b = bc >> 6, c = bc & 63;
    float* pre = pm + ((size_t)b*128 + c)*32768 + h*128;
    float* pim = pm + ((size_t)b*128 + 64 + c)*32768 + h*128;
    pre[lt] = base[lt]; pim[lt] = basei[lt];
    if (lt == 0) {
        pe[((size_t)b*128 + c)*256 + h]      = base[128];
        pe[((size_t)b*128 + 64 + c)*256 + h] = basei[128];
    }
}

__global__ __launch_bounds__(256,2)
void ffth_kernel(float* __restrict__ pm, float* __restrict__ pe, int inverse)
{
    __shared__ float sre[256*16], sim[256*16];   // [h][col]
    const int t = threadIdx.x;
    const int blk = blockIdx.x;
    const int chunk = blk % 9;
    const int bc = blk / 9;
    const int b = bc >> 6, c = bc & 63;
    const int col = t & 15;
    const int hb = t >> 4;
    const bool edge = (chunk == 8);
    const bool valid = edge ? (col == 0) : true;
    const int k = chunk*16 + col;
    float* pre; float* pim; int hstride;
    if (edge) {
        pre = pe + ((size_t)b*128 + c)*256;
        pim = pe + ((size_t)b*128 + 64 + c)*256;
        hstride = 1;
    } else {
        pre = pm + ((size_t)b*128 + c)*32768 + k;
        pim = pm + ((size_t)b*128 + 64 + c)*32768 + k;
        hstride = 128;
    }
    for (int hh = 0; hh < 16; hh++) {
        int h = hh*16 + hb;
        float vr = 0.f, vi = 0.f;
        if (valid) { vr = pre[h*hstride]; vi = pim[h*hstride]; }
        sre[h*16+col] = vr; sim[h*16+col] = vi;
    }
    __syncthreads();
    if (!inverse) {
        for (int s=8; s>=1; s--) {
            int m = 1<<s, half = m>>1;
            for (int it=0; it<8; it++) {
                int task = it*256 + t;
                int cl = task & 15;
                int bf = task >> 4;
                int j = bf & (half-1);
                int grp = bf >> (s-1);
                int i1 = grp*m + j, i2 = i1 + half;
                float ang = -6.283185307179586f * (float)j / (float)m;
                float sn, cs; __sincosf(ang, &sn, &cs);
                float ar = sre[i1*16+cl], ai = sim[i1*16+cl];
                float br = sre[i2*16+cl], bi = sim[i2*16+cl];
                float dr = ar - br, di = ai - bi;
                sre[i1*16+cl] = ar + br; sim[i1*16+cl] = ai + bi;
                sre[i2*16+cl] = cs*dr - sn*di;
                sim[i2*16+cl] = cs*di + sn*dr;
            }
            __syncthreads();
        }
    } else {
        for (int s=1; s<=8; s++) {
            int m = 1<<s, half = m>>1;
            for (int it=0; it<8; it++) {
                int task = it*256 + t;
                int cl = task & 15;
                int bf = task >> 4;
                int j = bf & (half-1);
                int grp = bf >> (s-1);
                int i1 = grp*m + j, i2 = i1 + half;
                float ang = 6.283185307179586f * (float)j / (float)m;
                float sn, cs; __sincosf(ang, &sn, &cs);
                float ar = sre[i1*16+cl], ai = sim[i1*16+cl];
                float br = sre[i2*16+cl], bi = sim[i2*16+cl];
                float tr = cs*br - sn*bi, ti = cs*bi + sn*br;
                sre[i1*16+cl] = ar + tr; sim[i1*16+cl] = ai + ti;
                sre[i2*16+cl] = ar - tr; sim[i2*16+cl] = ai - ti;
            }
            __syncthreads();
        }
    }
    const float scale = inverse ? (1.0f/256.0f) : 1.0f;
    for (int hh = 0; hh < 16; hh++) {
        int h = hh*16 + hb;
        if (valid) {
            pre[h*hstride] = sre[h*16+col]*scale;
            pim[h*hstride] = sim[h*16+col]*scale;
        }
    }
}

__global__ __launch_bounds__(256,4)
void irfftw_kernel(const float* __restrict__ pm, const float* __restrict__ pe,
                   float* __restrict__ outp)
{
    __shared__ float sre[2*256], sim[2*256];
    const int t = threadIdx.x;
    const int r = t >> 7, lt = t & 127;
    const int row = blockIdx.x*2 + r;
    const int bc = row >> 8, h = row & 255;
    const int b = bc >> 6, c = bc & 63;
    const float* pre = pm + ((size_t)b*128 + c)*32768 + h*128;
    const float* pim = pm + ((size_t)b*128 + 64 + c)*32768 + h*128;
    float* base = sre + r*256; float* basei = sim + r*256;
    {
        float xr = pre[lt], xi = pim[lt];
        int d1 = __brev((unsigned)lt) >> 24;
        base[d1] = xr; basei[d1] = xi;
        int k2 = lt + 128;
        int d2 = __brev((unsigned)k2) >> 24;
        float yr, yi;
        if (lt == 0) {
            yr = pe[((size_t)b*128 + c)*256 + h];
            yi = pe[((size_t)b*128 + 64 + c)*256 + h];
        } else {
            yr = pre[128-lt]; yi = -pim[128-lt];
        }
        base[d2] = yr; basei[d2] = yi;
    }
    __syncthreads();
    for (int s=1; s<=8; s++) {
        int m = 1<<s, half = m>>1;
        int j = lt & (half-1);
        int grp = lt >> (s-1);
        int i1 = grp*m + j, i2 = i1 + half;
        float ang = 6.283185307179586f * (float)j / (float)m;
        float sn, cs; __sincosf(ang, &sn, &cs);
        float ar = base[i1], ai = basei[i1];
        float br = base[i2], bi = basei[i2];
        float tr = cs*br - sn*bi, ti = cs*bi + sn*br;
        base[i1] = ar + tr; basei[i1] = ai + ti;
        base[i2] = ar - tr; basei[i2] = ai - ti;
        __syncthreads();
    }
    float* op = outp + (size_t)bc*HW + h*256;
    op[lt]     = base[lt]     * (1.0f/256.0f);
    op[lt+128] = base[lt+128] * (1.0f/256.0f);
}

// ======================= attention gram reduction (4 heads / launch) ==========
__global__ __launch_bounds__(256,2)
void gram4_kernel(const float* __restrict__ q, int q_cs, int q_choff,
                  const float* __restrict__ k, int k_cs, int k_choff,
                  int head_base,
                  float* __restrict__ G, float* __restrict__ qq, float* __restrict__ kk)
{
    const int blk = blockIdx.x;
    const int chunk = blk & 63;
    const int bhl = blk >> 6;        // 0..15
    const int b = bhl >> 2, lh = bhl & 3;
    const int g = head_base + lh;
    const int t = threadIdx.x;
    const int p0 = chunk * 1024;
    const float* qb = q + ((size_t)b*q_cs + q_choff + lh*8)*HW;
    const float* kb = k + ((size_t)b*k_cs + k_choff + lh*8)*HW;
    float gm[8][8], sq[8], sk[8];
    #pragma unroll
    for (int c=0;c<8;c++){ sq[c]=0.f; sk[c]=0.f;
        #pragma unroll
        for (int d=0;d<8;d++) gm[c][d]=0.f; }
    for (int i=0;i<4;i++) {
        const int p = p0 + i*256 + t;
        float qa[8], ka[8];
        #pragma unroll
        for (int c=0;c<8;c++){ qa[c]=qb[(size_t)c*HW+p]; ka[c]=kb[(size_t)c*HW+p]; }
        #pragma unroll
        for (int c=0;c<8;c++) {
            sq[c]=fmaf(qa[c],qa[c],sq[c]);
            sk[c]=fmaf(ka[c],ka[c],sk[c]);
            #pragma unroll
            for (int d=0;d<8;d++) gm[c][d]=fmaf(qa[c],ka[d],gm[c][d]);
        }
    }
    __shared__ float red[4][88];
    const int wv = t >> 6, ln = t & 63;
    #pragma unroll
    for (int c=0;c<8;c++){
        #pragma unroll
        for (int d=0;d<8;d++){
            float v = gm[c][d];
            #pragma unroll
            for (int off=32; off>=1; off>>=1) v += __shfl_down(v, off);
            if (ln==0) red[wv][c*8+d] = v;
        }
    }
    #pragma unroll
    for (int c=0;c<8;c++){
        float v = sq[c];
        #pragma unroll
        for (int off=32; off>=1; off>>=1) v += __shfl_down(v, off);
        if (ln==0) red[wv][64+c] = v;
        float u = sk[c];
        #pragma unroll
        for (int off=32; off>=1; off>>=1) u += __shfl_down(u, off);
        if (ln==0) red[wv][72+c] = u;
    }
    __syncthreads();
    if (t < 80) {
        float s = red[0][t] + red[1][t] + red[2][t] + red[3][t];
        const size_t bh = (size_t)b*8 + g;
        if (t < 64)      atomicAdd(&G[bh*64 + t], s);
        else if (t < 72) atomicAdd(&qq[bh*8 + (t-64)], s);
        else             atomicAdd(&kk[bh*8 + (t-72)], s);
    }
}

// ======================= softmax + fold proj into per-batch M =================
__global__ void attnmat_kernel(const float* __restrict__ G, const float* __restrict__ qq,
                               const float* __restrict__ kk, const float* __restrict__ temp,
                               const float* __restrict__ projw, float* __restrict__ M)
{
    __shared__ float A[2048];   // [bh][c][d]
    const int t = threadIdx.x;
    for (int i = t; i < 2048; i += 256) {
        int d = i & 7, c = (i>>3)&7, bh = i>>6;
        int h = bh & 7;
        float nq = fmaxf(sqrtf(qq[bh*8+c]), 1e-12f);
        float nk = fmaxf(sqrtf(kk[bh*8+d]), 1e-12f);
        A[i] = G[i] / (nq*nk) * temp[h];
    }
    __syncthreads();
    {
        int base = t*8;
        float mx = -1e30f;
        #pragma unroll
        for (int d=0;d<8;d++) mx = fmaxf(mx, A[base+d]);
        float e[8]; float sum = 0.f;
        #pragma unroll
        for (int d=0;d<8;d++){ e[d] = __expf(A[base+d]-mx); sum += e[d]; }
        float inv = 1.0f/sum;
        #pragma unroll
        for (int d=0;d<8;d++) A[base+d] = e[d]*inv;
    }
    __syncthreads();
    for (int i=t; i<16384; i+=256) {
        int hd = i & 63, co = (i>>6)&63, b = i>>12;
        int h = hd>>3, d = hd&7;
        float s = 0.f;
        #pragma unroll
        for (int c=0;c<8;c++)
            s = fmaf(projw[co*64 + h*8 + c], A[((b*8+h)*8+c)*8 + d], s);
        M[i] = s;
    }
}

// ======================= final: pw(64->128)+bias+sigmoid, gate, nan_to_num ====
__global__ __launch_bounds__(256,4)
void fuse_final_kernel(const float* __restrict__ t2, int t2_cs, int t2_choff,
                       const float* __restrict__ w, const float* __restrict__ bias,
                       const float* __restrict__ fre, const float* __restrict__ spa,
                       float* __restrict__ outp)
{
    __shared__ float s_w[64*128];   // [ci][co], co in 0..127 (32 KB)
    const int t = threadIdx.x, lane = t & 63, wv = t >> 6;
    const int b = blockIdx.y;
    const int p0 = blockIdx.x * 128;
    for (int idx=t; idx<8192; idx+=256){
        int co = idx & 127, ci = idx >> 7;
        s_w[ci*128 + co] = w[(size_t)co*64 + ci];
    }
    __syncthreads();
    const int wco = wv*16;
    float2 a1[16], a2[16];
    #pragma unroll
    for (int c=0;c<16;c++){
        float b1 = bias[wco+c], b2 = bias[64+wco+c];
        a1[c] = make_float2(b1,b1); a2[c] = make_float2(b2,b2);
    }
    const float* ip = t2 + ((size_t)b*t2_cs + t2_choff)*HW + p0 + lane*2;
    for (int ci=0; ci<64; ci++){
        float2 x = *(const float2*)(ip + (size_t)ci*HW);
        const float4* w1 = (const float4*)&s_w[ci*128 + wco];
        const float4* w2 = (const float4*)&s_w[ci*128 + 64 + wco];
        #pragma unroll
        for (int c4=0;c4<4;c4++){
            float4 u = w1[c4], v = w2[c4];
            a1[c4*4+0].x = fmaf(u.x,x.x,a1[c4*4+0].x); a1[c4*4+0].y = fmaf(u.x,x.y,a1[c4*4+0].y);
            a1[c4*4+1].x = fmaf(u.y,x.x,a1[c4*4+1].x); a1[c4*4+1].y = fmaf(u.y,x.y,a1[c4*4+1].y);
            a1[c4*4+2].x = fmaf(u.z,x.x,a1[c4*4+2].x); a1[c4*4+2].y = fmaf(u.z,x.y,a1[c4*4+2].y);
            a1[c4*4+3].x = fmaf(u.w,x.x,a1[c4*4+3].x); a1[c4*4+3].y = fmaf(u.w,x.y,a1[c4*4+3].y);
            a2[c4*4+0].x = fmaf(v.x,x.x,a2[c4*4+0].x); a2[c4*4+0].y = fmaf(v.x,x.y,a2[c4*4+0].y);
            a2[c4*4+1].x = fmaf(v.y,x.x,a2[c4*4+1].x); a2[c4*4+1].y = fmaf(v.y,x.y,a2[c4*4+1].y);
            a2[c4*4+2].x = fmaf(v.z,x.x,a2[c4*4+2].x); a2[c4*4+2].y = fmaf(v.z,x.y,a2[c4*4+2].y);
            a2[c4*4+3].x = fmaf(v.w,x.x,a2[c4*4+3].x); a2[c4*4+3].y = fmaf(v.w,x.y,a2[c4*4+3].y);
        }
    }
    #pragma unroll
    for (int c=0;c<16;c++){
        int co = wco + c;
        float s1x = 1.0f/(1.0f+__expf(-a1[c].x)), s1y = 1.0f/(1.0f+__expf(-a1[c].y));
        float s2x = 1.0f/(1.0f+__expf(-a2[c].x)), s2y = 1.0f/(1.0f+__expf(-a2[c].y));
        size_t off = ((size_t)b*64 + co)*HW + p0 + lane*2;
        float2 f = *(const float2*)(fre + off);
        float2 s = *(const float2*)(spa + off);
        float rx = f.x*s1x + s2x*s.x;
        float ry = f.y*s1y + s2y*s.y;
        if (!__builtin_isfinite(rx)) rx = 1e-5f;
        if (!__builtin_isfinite(ry)) ry = 1e-5f;
        *(float2*)(outp + off) = make_float2(rx, ry);
    }
}

// =============================== launcher =====================================
extern "C" void kernel_launch(void* const* d_in, const int* in_sizes, int n_in,
                              void* d_out, int out_size, void* d_ws, size_t ws_size,
                              hipStream_t stream) {
    const float* x0      = (const float*)d_in[0];
    const float* x1      = (const float*)d_in[1];
    const float* rl_w1   = (const float*)d_in[2];
    const float* rl_b1   = (const float*)d_in[3];
    const float* rl_w2   = (const float*)d_in[4];
    const float* rl_b2   = (const float*)d_in[5];
    const float* rg_w1   = (const float*)d_in[6];
    const float* rg_w2   = (const float*)d_in[7];
    const float* att_temp= (const float*)d_in[8];
    const float* kv_w    = (const float*)d_in[9];
    const float* kv_dw   = (const float*)d_in[10];
    const float* q_w     = (const float*)d_in[11];
    const float* q_dw    = (const float*)d_in[12];
    const float* proj_w  = (const float*)d_in[13];
    const float* f1_dw   = (const float*)d_in[14];
    const float* f1_dwb  = (const float*)d_in[15];
    const float* f1_pw   = (const float*)d_in[16];
    const float* f1_pwb  = (const float*)d_in[17];
    const float* f2_dw   = (const float*)d_in[18];
    const float* f2_dwb  = (const float*)d_in[19];
    const float* f2_pw   = (const float*)d_in[20];
    const float* f2_pwb  = (const float*)d_in[21];
    float* out = (float*)d_out;
    float* ws  = (float*)d_ws;

    const size_t A = (size_t)4*64*HW;       // 16,777,216 floats (64 MB)
    float* R0   = ws;                        // scratch A (freq main buffer)
    float* R1   = ws + A;                    // scratch A
    float* spa  = ws + 2*A;                  // persistent A
    float* PFe  = ws + 3*A;                  // Nyquist col: 4*128*256 = 131072
    float* PFe2 = PFe + 131072;              // Nyquist scratch
    float* G    = PFe2 + 131072;             // 2048
    float* qqv  = G + 2048;                  // 256
    float* kkv  = qqv + 256;                 // 256
    float* M    = kkv + 256;                 // 16384
    unsigned short* wbf = (unsigned short*)(M + 16384);  // 2*36864 bf16
    float* fre  = out;                       // fre lives in d_out

    const dim3 g_pw_hw(256, 4, 1);           // pw over HW, COTILE==COUT
    const dim3 g_pw_fq128(128, 4, 1);        // freq main, COTILE=128 single pass
    const dim3 g_pw_fe(1, 4, 2);             // freq edge
    const dim3 dwg64(64*64, 4);
    const dim3 dwg32(32*64, 4);

    // ---------- weight prep for MFMA convs ----------
    wprep_kernel<<<288,256,0,stream>>>(rl_w1, rl_w2, wbf);

    // ---------- Stage 1: ResBlock_L -> fre (in d_out) ----------
    conv3x3_mfma_kernel<<<1024,256,0,stream>>>(x0, wbf,         rl_b1, nullptr, R0);
    conv3x3_mfma_kernel<<<1024,256,0,stream>>>(R0, wbf + 36864, rl_b2, x0,      fre);

    // ---------- Stage 2: ResBlock_G -> spa ----------
    rfftw_kernel<<<32768,256,0,stream>>>(x1, R0, PFe);
    ffth_kernel<<<2304,256,0,stream>>>(R0, PFe, 0);
    pw_kernel<128,128><<<g_pw_fq128,256,0,stream>>>(R0,128,0,  R1,128,0,  rg_w1,0, nullptr, nullptr, 1, 32768);
    pw_kernel<128,64><<<g_pw_fe,256,0,stream>>>(PFe,128,0, PFe2,128,0, rg_w1,0, nullptr, nullptr, 1, 256);
    pw_kernel<128,128><<<g_pw_fq128,256,0,stream>>>(R1,128,0,  R0,128,0,  rg_w2,0, nullptr, nullptr, 0, 32768);
    pw_kernel<128,64><<<g_pw_fe,256,0,stream>>>(PFe2,128,0, PFe,128,0, rg_w2,0, nullptr, nullptr, 0, 256);
    ffth_kernel<<<2304,256,0,stream>>>(R0, PFe, 1);
    irfftw_kernel<<<32768,256,0,stream>>>(R0, PFe, spa);

    // ---------- attention (shared weights), applied twice ----------
    auto attention = [&](const float* xq, const float* ykv, float* io) {
        hipMemsetAsync(G, 0, 2560*sizeof(float), stream);
        for (int hh = 0; hh < 2; hh++) {
            const int cb = hh*32;
            // k32 = dw(pw(ykv, kv_w rows cb..cb+31))
            pw_kernel<64,32><<<g_pw_hw,256,0,stream>>>(ykv,64,0, R0,32,0, kv_w + (size_t)cb*64, 0, nullptr, nullptr, 0, HW);
            dw3x3_kernel<<<dwg32,256,0,stream>>>(R0,32,0, R1,64,0,  kv_dw, cb, nullptr);
            // q32 = dw(pw(xq, q_w rows cb..cb+31))
            pw_kernel<64,32><<<g_pw_hw,256,0,stream>>>(xq,64,0,  R0,32,0, q_w + (size_t)cb*64, 0, nullptr, nullptr, 0, HW);
            dw3x3_kernel<<<dwg32,256,0,stream>>>(R0,32,0, R1,64,32, q_dw, cb, nullptr);
            gram4_kernel<<<1024,256,0,stream>>>(R1,64,32, R1,64,0, hh*4, G, qqv, kkv);
        }
        attnmat_kernel<<<1,256,0,stream>>>(G, qqv, kkv, att_temp, proj_w, M);
        // v = dw(pw(ykv, kv_w rows 64..127))
        pw_kernel<64,64><<<g_pw_hw,256,0,stream>>>(ykv,64,0, R0,64,0, kv_w + (size_t)64*64, 0, nullptr, nullptr, 0, HW);
        dw3x3_kernel<<<dwg64,256,0,stream>>>(R0,64,0, R1,64,0, kv_dw, 64, nullptr);
        // io = M_b * v + io   (proj folded into M; in-place residual safe)
        pw_kernel<64,64><<<g_pw_hw,256,0,stream>>>(R1,64,0, io,64,0, M, 4096, nullptr, io, 0, HW);
    };
    attention(fre, spa, fre);   // fre = att(fre, spa) + fre
    attention(spa, fre, spa);   // spa = att(spa, fre_new) + spa

    // ---------- Stage 5: fuse (R0..R1 as one [b][128][HW] buffer) -------------
    float* W128 = R0;
    dw3x3_kernel<<<dwg64,256,0,stream>>>(fre,64,0, W128,128,0,  f1_dw, 0,  f1_dwb);
    dw3x3_kernel<<<dwg64,256,0,stream>>>(spa,64,0, W128,128,64, f1_dw, 64, f1_dwb);
    // pw 128->64 +bias, in-place into ch0..63 of W128 (z==1, block-local tiles)
    pw_kernel<128,64><<<g_pw_hw,256,0,stream>>>(W128,128,0, W128,128,0, f1_pw,0, f1_pwb, nullptr, 0, HW);
    // dw3x3 64ch +bias: read ch0..63, write ch64..127 (disjoint)
    dw3x3_kernel<<<dwg64,256,0,stream>>>(W128,128,0, W128,128,64, f2_dw, 0, f2_dwb);
    // pw 64->128 +bias, sigmoid, gate, nan_to_num -> out (in-place with fre)
    fuse_final_kernel<<<dim3(512,4),256,0,stream>>>(W128,128,64, f2_pw, f2_pwb, fre, spa, out);
    (void)in_sizes; (void)n_in; (void)out_size; (void)ws_size;
}

// Round 3
// 1541.269 us; speedup vs baseline: 1.3084x; 1.1705x over previous
//
#include <hip/hip_runtime.h>

#define HW 65536            // 256*256

typedef __attribute__((ext_vector_type(8))) _Float16 f16x8;
typedef __attribute__((ext_vector_type(4))) float floatx4;

__device__ inline unsigned short f2bf(float f){
    unsigned u = __builtin_bit_cast(unsigned, f);
    unsigned r = u + 0x7FFFu + ((u>>16)&1u);
    return (unsigned short)(r>>16);
}
__device__ inline unsigned short f2h(float f){
    return __builtin_bit_cast(unsigned short, (_Float16)f);
}

// ============ conv3x3 weight prep: OIHW fp32 -> [conv][ch][tap][co][ci32] f16 =
__global__ void wprep_kernel(const float* __restrict__ w1, const float* __restrict__ w2,
                             unsigned short* __restrict__ wbf)
{
    int idx = blockIdx.x*256 + threadIdx.x;   // < 2*36864
    const float* src = (idx < 36864) ? w1 : w2;
    int l = idx % 36864;
    int ch = l / 18432;
    int r  = l % 18432;
    int tap = r >> 11;            // /2048
    int co  = (r >> 5) & 63;
    int ci  = r & 31;
    wbf[idx] = f2h(src[co*576 + (ch*32+ci)*9 + tap]);
}

// ============ pw weight pack: [co][ci] fp32 -> [ci/32][co][ci32] f16 ==========
__global__ void wpack_kernel(const float* __restrict__ src, unsigned short* __restrict__ dst,
                             int CO, int CI)
{
    int idx = blockIdx.x*256 + threadIdx.x;
    if (idx >= CO*CI) return;
    int ci = idx % CI, co = idx / CI;
    dst[((size_t)(ci>>5)*CO + co)*32 + (ci&31)] = f2h(src[idx]);
}

// ======== dense 3x3 conv 64->64 via f16 MFMA, bias+relu (+res), fp32 io =======
__global__ __launch_bounds__(256,2)
void conv3x3_mfma_kernel(const float* __restrict__ in, const unsigned short* __restrict__ wbf,
                         const float* __restrict__ bias, const float* __restrict__ res,
                         float* __restrict__ out)
{
    __shared__ __align__(16) unsigned short s_in[6*66*72];   // 57024 B
    const int t = threadIdx.x;
    const int lane = t & 63, wv = t >> 6;
    const int n = lane & 15, q = lane >> 4;
    const int blk = blockIdx.x;
    const int xt = blk & 3, yt = (blk>>2) & 63, b = blk >> 8;
    const int x0 = xt*64, y0 = yt*4;

    const float* inb = in + (size_t)b*64*HW;

    // ---- stage 6 rows x 66 cols x 64 ci, fp32 -> f16, layout [row][xx][ci] ----
    {
        const int xq = t & 15;             // x-group of 4
        const int u0 = t >> 4;             // 0..15, composite ci/row base
        const float* gp0 = inb + x0 + xq*4;
        float4 tmp[12];
        #pragma unroll
        for (int ch = 0; ch < 2; ch++) {
            #pragma unroll
            for (int i = 0; i < 12; i++) {
                int u = u0 + (ch*12 + i)*16;     // 0..383
                int ci = u & 63, row = u >> 6;
                int gy = y0 + row - 1;
                float4 v = make_float4(0.f,0.f,0.f,0.f);
                if (gy >= 0 && gy < 256)
                    v = *(const float4*)(gp0 + (size_t)ci*HW + (size_t)gy*256);
                tmp[i] = v;
            }
            #pragma unroll
            for (int i = 0; i < 12; i++) {
                int u = u0 + (ch*12 + i)*16;
                int ci = u & 63, row = u >> 6;
                unsigned short* d = &s_in[(row*66 + xq*4 + 1)*72 + ci];
                d[0]   = f2h(tmp[i].x);
                d[72]  = f2h(tmp[i].y);
                d[144] = f2h(tmp[i].z);
                d[216] = f2h(tmp[i].w);
            }
        }
        // halo columns
        float hv[3];
        #pragma unroll
        for (int i = 0; i < 3; i++) {
            int idx = i*256 + t;           // < 768
            int ci = idx & 63;
            int side = (idx >> 6) & 1;
            int row = idx >> 7;
            int gx = x0 - 1 + side*65;
            int gy = y0 + row - 1;
            float v = 0.f;
            if (gx >= 0 && gx < 256 && gy >= 0 && gy < 256)
                v = inb[(size_t)ci*HW + (size_t)gy*256 + gx];
            hv[i] = v;
        }
        #pragma unroll
        for (int i = 0; i < 3; i++) {
            int idx = i*256 + t;
            int ci = idx & 63;
            int side = (idx >> 6) & 1;
            int row = idx >> 7;
            int xx = side ? 65 : 0;
            s_in[(row*66 + xx)*72 + ci] = f2h(hv[i]);
        }
    }
    __syncthreads();

    floatx4 zero = {0.f,0.f,0.f,0.f};
    floatx4 acc[4][4];
    #pragma unroll
    for (int y=0;y<4;y++)
        #pragma unroll
        for (int s=0;s<4;s++) acc[y][s] = zero;

    for (int kk = 0; kk < 2; kk++) {
        f16x8 af[9];
        #pragma unroll
        for (int tap=0; tap<9; tap++)
            af[tap] = *(const f16x8*)&wbf[kk*18432 + tap*2048 + (wv*16 + n)*32 + q*8];
        #pragma unroll
        for (int s=0;s<4;s++){
            #pragma unroll
            for (int dx=0;dx<3;dx++){
                f16x8 bf[6];
                #pragma unroll
                for (int r6=0;r6<6;r6++)
                    bf[r6] = *(const f16x8*)&s_in[(r6*66 + s*16 + n + dx)*72 + kk*32 + q*8];
                #pragma unroll
                for (int dy=0;dy<3;dy++){
                    #pragma unroll
                    for (int y=0;y<4;y++)
                        acc[y][s] = __builtin_amdgcn_mfma_f32_16x16x32_f16(
                            af[dy*3+dx], bf[y+dy], acc[y][s], 0,0,0);
                }
            }
        }
    }

    #pragma unroll
    for (int y=0;y<4;y++){
        #pragma unroll
        for (int s=0;s<4;s++){
            #pragma unroll
            for (int r=0;r<4;r++){
                int co = wv*16 + q*4 + r;
                int px = x0 + s*16 + n;
                size_t off = ((size_t)b*64+co)*HW + (size_t)(y0+y)*256 + px;
                float v = fmaxf(acc[y][s][r] + bias[co], 0.f);
                if (res) v += res[off];
                out[off] = v;
            }
        }
    }
}

// =================== pointwise (1x1) conv via f16 MFMA ========================
// GEMM out[co,p] = sum_ci w[co,ci] * in[ci,p].  Activations staged fp32->f16 in
// LDS [px][ci] stride 72 (proven layout); weights pre-packed [kk][co][32] f16.
// COTILE=32: 2 co-waves x 2 px-groups, PXT=512
// COTILE=64: 4 co-waves, PXT=256
// COTILE=128: 4 co-waves x 2 co-halves, PXT=128
template<int CIN, int COTILE>
__global__ __launch_bounds__(256,2)
void pw_mfma_kernel(const float* __restrict__ in, int in_cs, int in_choff,
                    float* __restrict__ out, int out_cs, int out_choff,
                    const unsigned short* __restrict__ wp, int wbstride, int wtot, int co_base,
                    const float* __restrict__ bias,
                    const float* __restrict__ res, int relu_flag, int P)
{
    constexpr int PXT   = (COTILE==32) ? 512 : (COTILE==64 ? 256 : 128);
    constexpr int HCO   = (COTILE==128) ? 2 : 1;
    constexpr int SCNT  = (PXT >= 256) ? 16 : 8;      // px-frags per wave
    constexpr int NHALF = CIN/64;
    constexpr int NLD   = PXT*CIN/1024;               // float4 per thread
    constexpr int PXM   = PXT/4;

    __shared__ __align__(16) unsigned short s_a[NHALF][PXT*72];

    const int t = threadIdx.x;
    const int lane = t & 63, wv = t >> 6;
    const int n = lane & 15, q = lane >> 4;
    const int b = blockIdx.y;
    const int p0 = blockIdx.x * PXT;
    const int colb   = (COTILE==32) ? (wv&1)*16 : wv*16;
    const int pxbase = (COTILE==32) ? (wv>>1)*256 : 0;

    // ---- stage PXT px x CIN ci, fp32 -> f16 ----
    const float* ipb = in + ((size_t)b*in_cs + in_choff)*P + p0;
    {
        float4 tmp[8];
        for (int c0 = 0; c0 < NLD; c0 += 8) {
            #pragma unroll
            for (int i=0;i<8;i++){
                int idx = t + (c0+i)*256;
                int px4 = idx & (PXM-1), ci = idx / PXM;
                tmp[i] = *(const float4*)(ipb + (size_t)ci*P + px4*4);
            }
            #pragma unroll
            for (int i=0;i<8;i++){
                int idx = t + (c0+i)*256;
                int px4 = idx & (PXM-1), ci = idx / PXM;
                unsigned short* d = &s_a[ci>>6][(px4*4)*72 + (ci&63)];
                d[0]   = f2h(tmp[i].x);
                d[72]  = f2h(tmp[i].y);
                d[144] = f2h(tmp[i].z);
                d[216] = f2h(tmp[i].w);
            }
        }
    }
    __syncthreads();

    floatx4 zero = {0.f,0.f,0.f,0.f};
    floatx4 acc[HCO][SCNT];
    #pragma unroll
    for (int h=0;h<HCO;h++)
        #pragma unroll
        for (int s=0;s<SCNT;s++) acc[h][s] = zero;

    // A-fragments from packed weights (L2-hot)
    f16x8 af[CIN/32][HCO];
    const unsigned short* wpb = wp + (size_t)b*wbstride;
    #pragma unroll
    for (int kk=0;kk<CIN/32;kk++)
        #pragma unroll
        for (int h=0;h<HCO;h++)
            af[kk][h] = *(const f16x8*)&wpb[((size_t)kk*wtot + co_base + h*64 + colb + n)*32 + q*8];

    #pragma unroll
    for (int s=0;s<SCNT;s++){
        #pragma unroll
        for (int kk=0;kk<CIN/32;kk++){
            f16x8 bf = *(const f16x8*)&s_a[kk>>1][(pxbase + s*16 + n)*72 + (kk&1)*32 + q*8];
            #pragma unroll
            for (int h=0;h<HCO;h++)
                acc[h][s] = __builtin_amdgcn_mfma_f32_16x16x32_f16(af[kk][h], bf, acc[h][s], 0,0,0);
        }
    }

    // epilogue: D col=n16 -> px, row=q*4+r -> co_local
    #pragma unroll
    for (int h=0;h<HCO;h++){
        #pragma unroll
        for (int s=0;s<SCNT;s++){
            int px = p0 + pxbase + s*16 + n;
            #pragma unroll
            for (int r=0;r<4;r++){
                int col = h*64 + colb + q*4 + r;     // 0..COTILE-1
                size_t off = ((size_t)b*out_cs + out_choff + col)*P + px;
                float v = acc[h][s][r];
                if (bias) v += bias[col];
                if (relu_flag) v = fmaxf(v, 0.f);
                if (res) v += res[off];
                out[off] = v;
            }
        }
    }
}

// ======================= depthwise 3x3, pad 1, 4 px/thread =====================
__global__ __launch_bounds__(256,4)
void dw3x3_kernel(const float* __restrict__ in, int in_cs, int in_choff,
                  float* __restrict__ out, int out_cs, int out_choff,
                  const float* __restrict__ w, int w_choff,
                  const float* __restrict__ bias)
{
    const int c = blockIdx.x >> 6;
    const int p = ((blockIdx.x & 63) << 10) + threadIdx.x*4;
    const int x = p & 255, y = p >> 8;
    const int b = blockIdx.y;
    const float* ip = in + ((size_t)b*in_cs + in_choff + c)*HW;
    const float* wp = w + (size_t)(w_choff + c)*9;
    float row[3][6];
    #pragma unroll
    for (int dy=0; dy<3; dy++){
        int yy = y + dy - 1;
        if (yy < 0 || yy > 255){
            #pragma unroll
            for (int j=0;j<6;j++) row[dy][j]=0.f;
        } else {
            const float* rp = ip + yy*256;
            float4 m = *(const float4*)(rp + x);
            row[dy][1]=m.x; row[dy][2]=m.y; row[dy][3]=m.z; row[dy][4]=m.w;
            row[dy][0] = (x>0)   ? rp[x-1] : 0.f;
            row[dy][5] = (x<252) ? rp[x+4] : 0.f;
        }
    }
    float bv = bias ? bias[w_choff + c] : 0.f;
    float o[4] = {bv,bv,bv,bv};
    #pragma unroll
    for (int dy=0;dy<3;dy++){
        #pragma unroll
        for (int dx=0;dx<3;dx++){
            float wv = wp[dy*3+dx];
            #pragma unroll
            for (int i=0;i<4;i++) o[i] = fmaf(wv, row[dy][i+dx], o[i]);
        }
    }
    *(float4*)(out + ((size_t)b*out_cs + out_choff + c)*HW + p) =
        make_float4(o[0],o[1],o[2],o[3]);
}

// ======================= FFT kernels ==========================================
__global__ __launch_bounds__(256,4)
void rfftw_kernel(const float* __restrict__ x, float* __restrict__ pm,
                  float* __restrict__ pe)
{
    __shared__ float sre[2*256], sim[2*256];
    const int t = threadIdx.x;
    const int r = t >> 7, lt = t & 127;
    const int row = blockIdx.x*2 + r;
    const int bc = row >> 8, h = row & 255;
    const float* xp = x + (size_t)bc*HW + h*256;
    float* base = sre + r*256; float* basei = sim + r*256;
    {
        int i1 = lt, i2 = lt + 128;
        int r1 = __brev((unsigned)i1) >> 24, r2 = __brev((unsigned)i2) >> 24;
        base[r1] = xp[i1]; basei[r1] = 0.f;
        base[r2] = xp[i2]; basei[r2] = 0.f;
    }
    __syncthreads();
    for (int s=1; s<=8; s++) {
        int m = 1<<s, half = m>>1;
        int j = lt & (half-1);
        int grp = lt >> (s-1);
        int i1 = grp*m + j, i2 = i1 + half;
        float ang = -6.283185307179586f * (float)j / (float)m;
        float sn, cs; __sincosf(ang, &sn, &cs);
        float ar = base[i1], ai = basei[i1];
        float br = base[i2], bi = basei[i2];
        float tr = cs*br - sn*bi, ti = cs*bi + sn*br;
        base[i1] = ar + tr; basei[i1] = ai + ti;
        base[i2] = ar - tr; basei[i2] = ai - ti;
        __syncthreads();
    }
    const int b = bc >> 6, c = bc & 63;
    float* pre = pm + ((size_t)b*128 + c)*32768 + h*128;
    float* pim = pm + ((size_t)b*128 + 64 + c)*32768 + h*128;
    pre[lt] = base[lt]; pim[lt] = basei[lt];
    if (lt == 0) {
        pe[((size_t)b*128 + c)*256 + h]      = base[128];
        pe[((size_t)b*128 + 64 + c)*256 + h] = basei[128];
    }
}

__global__ __launch_bounds__(256,2)
void ffth_kernel(float* __restrict__ pm, float* __restrict__ pe, int inverse)
{
    __shared__ float sre[256*16], sim[256*16];   // [h][col]
    const int t = threadIdx.x;
    const int blk = blockIdx.x;
    const int chunk = blk % 9;
    const int bc = blk / 9;
    const int b = bc >> 6, c = bc & 63;
    const int col = t & 15;
    const int hb = t >> 4;
    const bool edge = (chunk == 8);
    const bool valid = edge ? (col == 0) : true;
    const int k = chunk*16 + col;
    float* pre; float* pim; int hstride;
    if (edge) {
        pre = pe + ((size_t)b*128 + c)*256;
        pim = pe + ((size_t)b*128 + 64 + c)*256;
        hstride = 1;
    } else {
        pre = pm + ((size_t)b*128 + c)*32768 + k;
        pim = pm + ((size_t)b*128 + 64 + c)*32768 + k;
        hstride = 128;
    }
    for (int hh = 0; hh < 16; hh++) {
        int h = hh*16 + hb;
        float vr = 0.f, vi = 0.f;
        if (valid) { vr = pre[h*hstride]; vi = pim[h*hstride]; }
        sre[h*16+col] = vr; sim[h*16+col] = vi;
    }
    __syncthreads();
    if (!inverse) {
        for (int s=8; s>=1; s--) {
            int m = 1<<s, half = m>>1;
            for (int it=0; it<8; it++) {
                int task = it*256 + t;
                int cl = task & 15;
                int bf = task >> 4;
                int j = bf & (half-1);
                int grp = bf >> (s-1);
                int i1 = grp*m + j, i2 = i1 + half;
                float ang = -6.283185307179586f * (float)j / (float)m;
                float sn, cs; __sincosf(ang, &sn, &cs);
                float ar = sre[i1*16+cl], ai = sim[i1*16+cl];
                float br = sre[i2*16+cl], bi = sim[i2*16+cl];
                float dr = ar - br, di = ai - bi;
                sre[i1*16+cl] = ar + br; sim[i1*16+cl] = ai + bi;
                sre[i2*16+cl] = cs*dr - sn*di;
                sim[i2*16+cl] = cs*di + sn*dr;
            }
            __syncthreads();
        }
    } else {
        for (int s=1; s<=8; s++) {
            int m = 1<<s, half = m>>1;
            for (int it=0; it<8; it++) {
                int task = it*256 + t;
                int cl = task & 15;
                int bf = task >> 4;
                int j = bf & (half-1);
                int grp = bf >> (s-1);
                int i1 = grp*m + j, i2 = i1 + half;
                float ang = 6.283185307179586f * (float)j / (float)m;
                float sn, cs; __sincosf(ang, &sn, &cs);
                float ar = sre[i1*16+cl], ai = sim[i1*16+cl];
                float br = sre[i2*16+cl], bi = sim[i2*16+cl];
                float tr = cs*br - sn*bi, ti = cs*bi + sn*br;
                sre[i1*16+cl] = ar + tr; sim[i1*16+cl] = ai + ti;
                sre[i2*16+cl] = ar - tr; sim[i2*16+cl] = ai - ti;
            }
            __syncthreads();
        }
    }
    const float scale = inverse ? (1.0f/256.0f) : 1.0f;
    for (int hh = 0; hh < 16; hh++) {
        int h = hh*16 + hb;
        if (valid) {
            pre[h*hstride] = sre[h*16+col]*scale;
            pim[h*hstride] = sim[h*16+col]*scale;
        }
    }
}

__global__ __launch_bounds__(256,4)
void irfftw_kernel(const float* __restrict__ pm, const float* __restrict__ pe,
                   float* __restrict__ outp)
{
    __shared__ float sre[2*256], sim[2*256];
    const int t = threadIdx.x;
    const int r = t >> 7, lt = t & 127;
    const int row = blockIdx.x*2 + r;
    const int bc = row >> 8, h = row & 255;
    const int b = bc >> 6, c = bc & 63;
    const float* pre = pm + ((size_t)b*128 + c)*32768 + h*128;
    const float* pim = pm + ((size_t)b*128 + 64 + c)*32768 + h*128;
    float* base = sre + r*256; float* basei = sim + r*256;
    {
        float xr = pre[lt], xi = pim[lt];
        int d1 = __brev((unsigned)lt) >> 24;
        base[d1] = xr; basei[d1] = xi;
        int k2 = lt + 128;
        int d2 = __brev((unsigned)k2) >> 24;
        float yr, yi;
        if (lt == 0) {
            yr = pe[((size_t)b*128 + c)*256 + h];
            yi = pe[((size_t)b*128 + 64 + c)*256 + h];
        } else {
            yr = pre[128-lt]; yi = -pim[128-lt];
        }
        base[d2] = yr; basei[d2] = yi;
    }
    __syncthreads();
    for (int s=1; s<=8; s++) {
        int m = 1<<s, half = m>>1;
        int j = lt & (half-1);
        int grp = lt >> (s-1);
        int i1 = grp*m + j, i2 = i1 + half;
        float ang = 6.283185307179586f * (float)j / (float)m;
        float sn, cs; __sincosf(ang, &sn, &cs);
        float ar = base[i1], ai = basei[i1];
        float br = base[i2], bi = basei[i2];
        float tr = cs*br - sn*bi, ti = cs*bi + sn*br;
        base[i1] = ar + tr; basei[i1] = ai + ti;
        base[i2] = ar - tr; basei[i2] = ai - ti;
        __syncthreads();
    }
    float* op = outp + (size_t)bc*HW + h*256;
    op[lt]     = base[lt]     * (1.0f/256.0f);
    op[lt+128] = base[lt+128] * (1.0f/256.0f);
}

// ======================= attention gram reduction (4 heads / launch) ==========
__global__ __launch_bounds__(256,2)
void gram4_kernel(const float* __restrict__ q, int q_cs, int q_choff,
                  const float* __restrict__ k, int k_cs, int k_choff,
                  int head_base,
                  float* __restrict__ G, float* __restrict__ qq, float* __restrict__ kk)
{
    const int blk = blockIdx.x;
    const int chunk = blk & 63;
    const int bhl = blk >> 6;        // 0..15
    const int b = bhl >> 2, lh = bhl & 3;
    const int g = head_base + lh;
    const int t = threadIdx.x;
    const int p0 = chunk * 1024;
    const float* qb = q + ((size_t)b*q_cs + q_choff + lh*8)*HW;
    const float* kb = k + ((size_t)b*k_cs + k_choff + lh*8)*HW;
    float gm[8][8], sq[8], sk[8];
    #pragma unroll
    for (int c=0;c<8;c++){ sq[c]=0.f; sk[c]=0.f;
        #pragma unroll
        for (int d=0;d<8;d++) gm[c][d]=0.f; }
    for (int i=0;i<4;i++) {
        const int p = p0 + i*256 + t;
        float qa[8], ka[8];
        #pragma unroll
        for (int c=0;c<8;c++){ qa[c]=qb[(size_t)c*HW+p]; ka[c]=kb[(size_t)c*HW+p]; }
        #pragma unroll
        for (int c=0;c<8;c++) {
            sq[c]=fmaf(qa[c],qa[c],sq[c]);
            sk[c]=fmaf(ka[c],ka[c],sk[c]);
            #pragma unroll
            for (int d=0;d<8;d++) gm[c][d]=fmaf(qa[c],ka[d],gm[c][d]);
        }
    }
    __shared__ float red[4][88];
    const int wv = t >> 6, ln = t & 63;
    #pragma unroll
    for (int c=0;c<8;c++){
        #pragma unroll
        for (int d=0;d<8;d++){
            float v = gm[c][d];
            #pragma unroll
            for (int off=32; off>=1; off>>=1) v += __shfl_down(v, off);
            if (ln==0) red[wv][c*8+d] = v;
        }
    }
    #pragma unroll
    for (int c=0;c<8;c++){
        float v = sq[c];
        #pragma unroll
        for (int off=32; off>=1; off>>=1) v += __shfl_down(v, off);
        if (ln==0) red[wv][64+c] = v;
        float u = sk[c];
        #pragma unroll
        for (int off=32; off>=1; off>>=1) u += __shfl_down(u, off);
        if (ln==0) red[wv][72+c] = u;
    }
    __syncthreads();
    if (t < 80) {
        float s = red[0][t] + red[1][t] + red[2][t] + red[3][t];
        const size_t bh = (size_t)b*8 + g;
        if (t < 64)      atomicAdd(&G[bh*64 + t], s);
        else if (t < 72) atomicAdd(&qq[bh*8 + (t-64)], s);
        else             atomicAdd(&kk[bh*8 + (t-72)], s);
    }
}

// ========= softmax + fold proj into per-batch M (packed f16 for MFMA pw) ======
__global__ void attnmat_kernel(const float* __restrict__ G, const float* __restrict__ qq,
                               const float* __restrict__ kk, const float* __restrict__ temp,
                               const float* __restrict__ projw, unsigned short* __restrict__ Mp)
{
    __shared__ float A[2048];   // [bh][c][d]
    const int t = threadIdx.x;
    for (int i = t; i < 2048; i += 256) {
        int d = i & 7, c = (i>>3)&7, bh = i>>6;
        int h = bh & 7;
        float nq = fmaxf(sqrtf(qq[bh*8+c]), 1e-12f);
        float nk = fmaxf(sqrtf(kk[bh*8+d]), 1e-12f);
        A[i] = G[i] / (nq*nk) * temp[h];
    }
    __syncthreads();
    {
        int base = t*8;
        float mx = -1e30f;
        #pragma unroll
        for (int d=0;d<8;d++) mx = fmaxf(mx, A[base+d]);
        float e[8]; float sum = 0.f;
        #pragma unroll
        for (int d=0;d<8;d++){ e[d] = __expf(A[base+d]-mx); sum += e[d]; }
        float inv = 1.0f/sum;
        #pragma unroll
        for (int d=0;d<8;d++) A[base+d] = e[d]*inv;
    }
    __syncthreads();
    for (int i=t; i<16384; i+=256) {
        int hd = i & 63, co = (i>>6)&63, b = i>>12;
        int h = hd>>3, d = hd&7;
        float s = 0.f;
        #pragma unroll
        for (int c=0;c<8;c++)
            s = fmaf(projw[co*64 + h*8 + c], A[((b*8+h)*8+c)*8 + d], s);
        // packed: [b][ci/32][co][ci&31], ci = hd
        Mp[(size_t)b*4096 + ((size_t)(hd>>5)*64 + co)*32 + (hd&31)] = f2h(s);
    }
}

// ==== final: pw(64->128) f16 MFMA + bias + sigmoid, gate, nan_to_num ==========
__global__ __launch_bounds__(256,2)
void fuse_final_mfma_kernel(const float* __restrict__ t2, int t2_cs, int t2_choff,
                            const unsigned short* __restrict__ wp,   // [2][128][32] f16
                            const float* __restrict__ bias,
                            const float* __restrict__ fre, const float* __restrict__ spa,
                            float* __restrict__ outp)
{
    __shared__ __align__(16) unsigned short s_a[128*72];
    const int t = threadIdx.x;
    const int lane = t & 63, wv = t >> 6;
    const int n = lane & 15, q = lane >> 4;
    const int b = blockIdx.y;
    const int p0 = blockIdx.x * 128;

    // stage 128 px x 64 ci
    const float* ipb = t2 + ((size_t)b*t2_cs + t2_choff)*HW + p0;
    {
        float4 tmp[8];
        #pragma unroll
        for (int i=0;i<8;i++){
            int idx = t + i*256;
            int px4 = idx & 31, ci = idx >> 5;
            tmp[i] = *(const float4*)(ipb + (size_t)ci*HW + px4*4);
        }
        #pragma unroll
        for (int i=0;i<8;i++){
            int idx = t + i*256;
            int px4 = idx & 31, ci = idx >> 5;
            unsigned short* d = &s_a[(px4*4)*72 + ci];
            d[0]   = f2h(tmp[i].x);
            d[72]  = f2h(tmp[i].y);
            d[144] = f2h(tmp[i].z);
            d[216] = f2h(tmp[i].w);
        }
    }
    __syncthreads();

    floatx4 zero = {0.f,0.f,0.f,0.f};
    floatx4 acc[2][8];
    #pragma unroll
    for (int h=0;h<2;h++)
        #pragma unroll
        for (int s=0;s<8;s++) acc[h][s] = zero;

    f16x8 af[2][2];
    #pragma unroll
    for (int kk=0;kk<2;kk++)
        #pragma unroll
        for (int h=0;h<2;h++)
            af[kk][h] = *(const f16x8*)&wp[((size_t)kk*128 + h*64 + wv*16 + n)*32 + q*8];

    #pragma unroll
    for (int s=0;s<8;s++){
        #pragma unroll
        for (int kk=0;kk<2;kk++){
            f16x8 bf = *(const f16x8*)&s_a[(s*16 + n)*72 + kk*32 + q*8];
            #pragma unroll
            for (int h=0;h<2;h++)
                acc[h][s] = __builtin_amdgcn_mfma_f32_16x16x32_f16(af[kk][h], bf, acc[h][s], 0,0,0);
        }
    }

    #pragma unroll
    for (int s=0;s<8;s++){
        int px = p0 + s*16 + n;
        #pragma unroll
        for (int r=0;r<4;r++){
            int c = wv*16 + q*4 + r;
            float g1 = acc[0][s][r] + bias[c];
            float g2 = acc[1][s][r] + bias[64+c];
            float s1 = 1.0f/(1.0f+__expf(-g1));
            float s2 = 1.0f/(1.0f+__expf(-g2));
            size_t off = ((size_t)b*64 + c)*HW + px;
            float f = fre[off], sp = spa[off];
            float v = f*s1 + s2*sp;
            if (!__builtin_isfinite(v)) v = 1e-5f;
            outp[off] = v;
        }
    }
}

// =============================== launcher =====================================
extern "C" void kernel_launch(void* const* d_in, const int* in_sizes, int n_in,
                              void* d_out, int out_size, void* d_ws, size_t ws_size,
                              hipStream_t stream) {
    const float* x0      = (const float*)d_in[0];
    const float* x1      = (const float*)d_in[1];
    const float* rl_w1   = (const float*)d_in[2];
    const float* rl_b1   = (const float*)d_in[3];
    const float* rl_w2   = (const float*)d_in[4];
    const float* rl_b2   = (const float*)d_in[5];
    const float* rg_w1   = (const float*)d_in[6];
    const float* rg_w2   = (const float*)d_in[7];
    const float* att_temp= (const float*)d_in[8];
    const float* kv_w    = (const float*)d_in[9];
    const float* kv_dw   = (const float*)d_in[10];
    const float* q_w     = (const float*)d_in[11];
    const float* q_dw    = (const float*)d_in[12];
    const float* proj_w  = (const float*)d_in[13];
    const float* f1_dw   = (const float*)d_in[14];
    const float* f1_dwb  = (const float*)d_in[15];
    const float* f1_pw   = (const float*)d_in[16];
    const float* f1_pwb  = (const float*)d_in[17];
    const float* f2_dw   = (const float*)d_in[18];
    const float* f2_dwb  = (const float*)d_in[19];
    const float* f2_pw   = (const float*)d_in[20];
    const float* f2_pwb  = (const float*)d_in[21];
    float* out = (float*)d_out;
    float* ws  = (float*)d_ws;

    const size_t A = (size_t)4*64*HW;       // 16,777,216 floats (64 MB)
    float* R0   = ws;                        // scratch A (freq main buffer)
    float* R1   = ws + A;                    // scratch A
    float* spa  = ws + 2*A;                  // persistent A
    float* PFe  = ws + 3*A;                  // Nyquist col: 4*128*256 = 131072
    float* PFe2 = PFe + 131072;              // Nyquist scratch
    float* G    = PFe2 + 131072;             // 2048
    float* qqv  = G + 2048;                  // 256
    float* kkv  = qqv + 256;                 // 256
    unsigned short* wbf = (unsigned short*)(kkv + 256);  // conv3x3: 2*36864 u16
    unsigned short* kvP = wbf + 2*36864;     // 2*128*32 = 8192
    unsigned short* qP  = kvP + 8192;        // 2*64*32  = 4096
    unsigned short* rg1P= qP  + 4096;        // 4*128*32 = 16384
    unsigned short* rg2P= rg1P+ 16384;       // 16384
    unsigned short* f1P = rg2P+ 16384;       // 4*64*32  = 8192
    unsigned short* f2P = f1P + 8192;        // 2*128*32 = 8192
    unsigned short* Mp  = f2P + 8192;        // 4*2*64*32 = 16384
    float* fre  = out;                       // fre lives in d_out

    const dim3 dwg64(64*64, 4);
    const dim3 dwg32(32*64, 4);

    // ---------- weight prep ----------
    wprep_kernel<<<288,256,0,stream>>>(rl_w1, rl_w2, wbf);
    wpack_kernel<<<32,256,0,stream>>>(kv_w,  kvP, 128, 64);
    wpack_kernel<<<16,256,0,stream>>>(q_w,   qP,   64, 64);
    wpack_kernel<<<64,256,0,stream>>>(rg_w1, rg1P,128,128);
    wpack_kernel<<<64,256,0,stream>>>(rg_w2, rg2P,128,128);
    wpack_kernel<<<32,256,0,stream>>>(f1_pw, f1P,  64,128);
    wpack_kernel<<<32,256,0,stream>>>(f2_pw, f2P, 128, 64);

    // ---------- Stage 1: ResBlock_L -> fre (in d_out) ----------
    conv3x3_mfma_kernel<<<1024,256,0,stream>>>(x0, wbf,         rl_b1, nullptr, R0);
    conv3x3_mfma_kernel<<<1024,256,0,stream>>>(R0, wbf + 36864, rl_b2, x0,      fre);

    // ---------- Stage 2: ResBlock_G -> spa ----------
    rfftw_kernel<<<32768,256,0,stream>>>(x1, R0, PFe);
    ffth_kernel<<<2304,256,0,stream>>>(R0, PFe, 0);
    pw_mfma_kernel<128,128><<<dim3(256,4),256,0,stream>>>(R0,128,0,  R1,128,0,  rg1P,0,128,0, nullptr, nullptr, 1, 32768);
    pw_mfma_kernel<128,128><<<dim3(2,4),  256,0,stream>>>(PFe,128,0, PFe2,128,0, rg1P,0,128,0, nullptr, nullptr, 1, 256);
    pw_mfma_kernel<128,128><<<dim3(256,4),256,0,stream>>>(R1,128,0,  R0,128,0,  rg2P,0,128,0, nullptr, nullptr, 0, 32768);
    pw_mfma_kernel<128,128><<<dim3(2,4),  256,0,stream>>>(PFe2,128,0, PFe,128,0, rg2P,0,128,0, nullptr, nullptr, 0, 256);
    ffth_kernel<<<2304,256,0,stream>>>(R0, PFe, 1);
    irfftw_kernel<<<32768,256,0,stream>>>(R0, PFe, spa);

    // ---------- attention (shared weights), applied twice ----------
    auto attention = [&](const float* xq, const float* ykv, float* io) {
        hipMemsetAsync(G, 0, 2560*sizeof(float), stream);
        for (int hh = 0; hh < 2; hh++) {
            const int cb = hh*32;
            // k32 = dw(pw(ykv, kv_w rows cb..cb+31))
            pw_mfma_kernel<64,32><<<dim3(128,4),256,0,stream>>>(ykv,64,0, R0,32,0, kvP,0,128,cb, nullptr, nullptr, 0, HW);
            dw3x3_kernel<<<dwg32,256,0,stream>>>(R0,32,0, R1,64,0,  kv_dw, cb, nullptr);
            // q32 = dw(pw(xq, q_w rows cb..cb+31))
            pw_mfma_kernel<64,32><<<dim3(128,4),256,0,stream>>>(xq,64,0,  R0,32,0, qP,0,64,cb, nullptr, nullptr, 0, HW);
            dw3x3_kernel<<<dwg32,256,0,stream>>>(R0,32,0, R1,64,32, q_dw, cb, nullptr);
            gram4_kernel<<<1024,256,0,stream>>>(R1,64,32, R1,64,0, hh*4, G, qqv, kkv);
        }
        attnmat_kernel<<<1,256,0,stream>>>(G, qqv, kkv, att_temp, proj_w, Mp);
        // v = dw(pw(ykv, kv_w rows 64..127))
        pw_mfma_kernel<64,64><<<dim3(256,4),256,0,stream>>>(ykv,64,0, R0,64,0, kvP,0,128,64, nullptr, nullptr, 0, HW);
        dw3x3_kernel<<<dwg64,256,0,stream>>>(R0,64,0, R1,64,0, kv_dw, 64, nullptr);
        // io = M_b * v + io   (proj folded into packed M; in-place residual safe)
        pw_mfma_kernel<64,64><<<dim3(256,4),256,0,stream>>>(R1,64,0, io,64,0, Mp,4096,64,0, nullptr, io, 0, HW);
    };
    attention(fre, spa, fre);   // fre = att(fre, spa) + fre
    attention(spa, fre, spa);   // spa = att(spa, fre_new) + spa

    // ---------- Stage 5: fuse (R0..R1 as one [b][128][HW] buffer) -------------
    float* W128 = R0;
    dw3x3_kernel<<<dwg64,256,0,stream>>>(fre,64,0, W128,128,0,  f1_dw, 0,  f1_dwb);
    dw3x3_kernel<<<dwg64,256,0,stream>>>(spa,64,0, W128,128,64, f1_dw, 64, f1_dwb);
    // pw 128->64 +bias, in-place into ch0..63 of W128 (block-local px tiles)
    pw_mfma_kernel<128,64><<<dim3(256,4),256,0,stream>>>(W128,128,0, W128,128,0, f1P,0,64,0, f1_pwb, nullptr, 0, HW);
    // dw3x3 64ch +bias: read ch0..63, write ch64..127 (disjoint)
    dw3x3_kernel<<<dwg64,256,0,stream>>>(W128,128,0, W128,128,64, f2_dw, 0, f2_dwb);
    // pw 64->128 +bias, sigmoid, gate, nan_to_num -> out (in-place with fre)
    fuse_final_mfma_kernel<<<dim3(512,4),256,0,stream>>>(W128,128,64, f2P, f2_pwb, fre, spa, out);
    (void)in_sizes; (void)n_in; (void)out_size; (void)ws_size;
}

// Round 4
// 1279.009 us; speedup vs baseline: 1.5767x; 1.2050x over previous
//
#include <hip/hip_runtime.h>

#define HW 65536            // 256*256

typedef __attribute__((ext_vector_type(8))) _Float16 f16x8;
typedef __attribute__((ext_vector_type(4))) float floatx4;

__device__ inline unsigned short f2h(float f){
    return __builtin_bit_cast(unsigned short, (_Float16)f);
}
__device__ inline float h2f(unsigned short h){
    return (float)__builtin_bit_cast(_Float16, h);
}

// ============ conv3x3 weight prep: OIHW fp32 -> [conv][ch][tap][co][ci32] f16 =
__global__ void wprep_kernel(const float* __restrict__ w1, const float* __restrict__ w2,
                             unsigned short* __restrict__ wbf)
{
    int idx = blockIdx.x*256 + threadIdx.x;   // < 2*36864
    const float* src = (idx < 36864) ? w1 : w2;
    int l = idx % 36864;
    int ch = l / 18432;
    int r  = l % 18432;
    int tap = r >> 11;            // /2048
    int co  = (r >> 5) & 63;
    int ci  = r & 31;
    wbf[idx] = f2h(src[co*576 + (ch*32+ci)*9 + tap]);
}

// ============ pw weight pack: [co][ci] fp32 -> [ci/32][co][ci32] f16 ==========
__global__ void wpack_kernel(const float* __restrict__ src, unsigned short* __restrict__ dst,
                             int CO, int CI)
{
    int idx = blockIdx.x*256 + threadIdx.x;
    if (idx >= CO*CI) return;
    int ci = idx % CI, co = idx / CI;
    dst[((size_t)(ci>>5)*CO + co)*32 + (ci&31)] = f2h(src[idx]);
}

// ======== dense 3x3 conv 64->64 via f16 MFMA, bias+relu (+res), fp32 io =======
__global__ __launch_bounds__(256,2)
void conv3x3_mfma_kernel(const float* __restrict__ in, const unsigned short* __restrict__ wbf,
                         const float* __restrict__ bias, const float* __restrict__ res,
                         float* __restrict__ out)
{
    __shared__ __align__(16) unsigned short s_in[6*66*72];   // 57024 B
    const int t = threadIdx.x;
    const int lane = t & 63, wv = t >> 6;
    const int n = lane & 15, q = lane >> 4;
    const int blk = blockIdx.x;
    const int xt = blk & 3, yt = (blk>>2) & 63, b = blk >> 8;
    const int x0 = xt*64, y0 = yt*4;

    const float* inb = in + (size_t)b*64*HW;

    // ---- stage 6 rows x 66 cols x 64 ci, fp32 -> f16, layout [row][xx][ci] ----
    {
        const int xq = t & 15;             // x-group of 4
        const int u0 = t >> 4;             // 0..15, composite ci/row base
        const float* gp0 = inb + x0 + xq*4;
        float4 tmp[12];
        #pragma unroll
        for (int ch = 0; ch < 2; ch++) {
            #pragma unroll
            for (int i = 0; i < 12; i++) {
                int u = u0 + (ch*12 + i)*16;     // 0..383
                int ci = u & 63, row = u >> 6;
                int gy = y0 + row - 1;
                float4 v = make_float4(0.f,0.f,0.f,0.f);
                if (gy >= 0 && gy < 256)
                    v = *(const float4*)(gp0 + (size_t)ci*HW + (size_t)gy*256);
                tmp[i] = v;
            }
            #pragma unroll
            for (int i = 0; i < 12; i++) {
                int u = u0 + (ch*12 + i)*16;
                int ci = u & 63, row = u >> 6;
                unsigned short* d = &s_in[(row*66 + xq*4 + 1)*72 + ci];
                d[0]   = f2h(tmp[i].x);
                d[72]  = f2h(tmp[i].y);
                d[144] = f2h(tmp[i].z);
                d[216] = f2h(tmp[i].w);
            }
        }
        // halo columns
        float hv[3];
        #pragma unroll
        for (int i = 0; i < 3; i++) {
            int idx = i*256 + t;           // < 768
            int ci = idx & 63;
            int side = (idx >> 6) & 1;
            int row = idx >> 7;
            int gx = x0 - 1 + side*65;
            int gy = y0 + row - 1;
            float v = 0.f;
            if (gx >= 0 && gx < 256 && gy >= 0 && gy < 256)
                v = inb[(size_t)ci*HW + (size_t)gy*256 + gx];
            hv[i] = v;
        }
        #pragma unroll
        for (int i = 0; i < 3; i++) {
            int idx = i*256 + t;
            int ci = idx & 63;
            int side = (idx >> 6) & 1;
            int row = idx >> 7;
            int xx = side ? 65 : 0;
            s_in[(row*66 + xx)*72 + ci] = f2h(hv[i]);
        }
    }
    __syncthreads();

    floatx4 zero = {0.f,0.f,0.f,0.f};
    floatx4 acc[4][4];
    #pragma unroll
    for (int y=0;y<4;y++)
        #pragma unroll
        for (int s=0;s<4;s++) acc[y][s] = zero;

    for (int kk = 0; kk < 2; kk++) {
        f16x8 af[9];
        #pragma unroll
        for (int tap=0; tap<9; tap++)
            af[tap] = *(const f16x8*)&wbf[kk*18432 + tap*2048 + (wv*16 + n)*32 + q*8];
        #pragma unroll
        for (int s=0;s<4;s++){
            #pragma unroll
            for (int dx=0;dx<3;dx++){
                f16x8 bf[6];
                #pragma unroll
                for (int r6=0;r6<6;r6++)
                    bf[r6] = *(const f16x8*)&s_in[(r6*66 + s*16 + n + dx)*72 + kk*32 + q*8];
                #pragma unroll
                for (int dy=0;dy<3;dy++){
                    #pragma unroll
                    for (int y=0;y<4;y++)
                        acc[y][s] = __builtin_amdgcn_mfma_f32_16x16x32_f16(
                            af[dy*3+dx], bf[y+dy], acc[y][s], 0,0,0);
                }
            }
        }
    }

    #pragma unroll
    for (int y=0;y<4;y++){
        #pragma unroll
        for (int s=0;s<4;s++){
            #pragma unroll
            for (int r=0;r<4;r++){
                int co = wv*16 + q*4 + r;
                int px = x0 + s*16 + n;
                size_t off = ((size_t)b*64+co)*HW + (size_t)(y0+y)*256 + px;
                float v = fmaxf(acc[y][s][r] + bias[co], 0.f);
                if (res) v += res[off];
                out[off] = v;
            }
        }
    }
}

// ============ fused pw(1x1,64->64 f16 MFMA) + dw(3x3) for attention ===========
// Tile: 64px x 4 rows x 64 co.  Grid: 4 xt * 64 yt * 4 b = 1024 blocks.
// MODE 0: store dw output (v).  MODE 1: store + kk atomics (k).
// MODE 2: no store; gram vs kin via wave shuffles, partials -> Gp (q).
template<int MODE>
__global__ __launch_bounds__(256,2)
void pwdw_kernel(const float* __restrict__ in,
                 const unsigned short* __restrict__ wp, int wtot, int co_base,
                 const float* __restrict__ dww, int dw_choff,
                 float* __restrict__ outp,
                 const float* __restrict__ kin,
                 float* __restrict__ Gp,
                 float* __restrict__ kkv)
{
    __shared__ __align__(16) unsigned short s_buf[400*72];   // 57600 B
    const int t = threadIdx.x;
    const int lane = t & 63, wv = t >> 6;
    const int n = lane & 15, q = lane >> 4;
    const int blk = blockIdx.x;
    const int xt = blk & 3, yt = (blk>>2) & 63, b = blk >> 8;
    const int x0 = xt*64, y0 = yt*4;
    const float* inb = in + (size_t)b*64*HW;

    // ---- Phase A: stage 6x66x64 fp32->f16, [px=row*66+col][ci] stride 72 ----
    {
        const int xq = t & 15;
        const int u0 = t >> 4;
        const float* gp0 = inb + x0 + xq*4;
        float4 tmp[12];
        #pragma unroll
        for (int ch = 0; ch < 2; ch++) {
            #pragma unroll
            for (int i = 0; i < 12; i++) {
                int u = u0 + (ch*12 + i)*16;
                int ci = u & 63, row = u >> 6;
                int gy = y0 + row - 1;
                float4 v = make_float4(0.f,0.f,0.f,0.f);
                if (gy >= 0 && gy < 256)
                    v = *(const float4*)(gp0 + (size_t)ci*HW + (size_t)gy*256);
                tmp[i] = v;
            }
            #pragma unroll
            for (int i = 0; i < 12; i++) {
                int u = u0 + (ch*12 + i)*16;
                int ci = u & 63, row = u >> 6;
                unsigned short* d = &s_buf[(row*66 + xq*4 + 1)*72 + ci];
                d[0]   = f2h(tmp[i].x);
                d[72]  = f2h(tmp[i].y);
                d[144] = f2h(tmp[i].z);
                d[216] = f2h(tmp[i].w);
            }
        }
        float hv[3];
        #pragma unroll
        for (int i = 0; i < 3; i++) {
            int idx = i*256 + t;
            int ci = idx & 63;
            int side = (idx >> 6) & 1;
            int row = idx >> 7;
            int gx = x0 - 1 + side*65;
            int gy = y0 + row - 1;
            float v = 0.f;
            if (gx >= 0 && gx < 256 && gy >= 0 && gy < 256)
                v = inb[(size_t)ci*HW + (size_t)gy*256 + gx];
            hv[i] = v;
        }
        #pragma unroll
        for (int i = 0; i < 3; i++) {
            int idx = i*256 + t;
            int ci = idx & 63;
            int side = (idx >> 6) & 1;
            int row = idx >> 7;
            int xx = side ? 65 : 0;
            s_buf[(row*66 + xx)*72 + ci] = f2h(hv[i]);
        }
    }
    __syncthreads();

    // ---- Phase B: pw MFMA over 25 px-groups (396 valid px), co = wv*16+.. ----
    floatx4 zero = {0.f,0.f,0.f,0.f};
    floatx4 acc[25];
    #pragma unroll
    for (int g=0;g<25;g++) acc[g] = zero;
    f16x8 af[2];
    #pragma unroll
    for (int kk=0;kk<2;kk++)
        af[kk] = *(const f16x8*)&wp[((size_t)(kk*wtot + co_base + wv*16 + n))*32 + q*8];
    #pragma unroll
    for (int g=0;g<25;g++){
        #pragma unroll
        for (int kk=0;kk<2;kk++){
            f16x8 bf = *(const f16x8*)&s_buf[(g*16 + n)*72 + kk*32 + q*8];
            acc[g] = __builtin_amdgcn_mfma_f32_16x16x32_f16(af[kk], bf, acc[g], 0,0,0);
        }
    }
    __syncthreads();   // all staging reads done before P overwrite

    // ---- Phase C: P[co][402] f16 (bank-stride 201 -> conflict-free reads) ----
    #pragma unroll
    for (int g=0;g<25;g++){
        #pragma unroll
        for (int r=0;r<4;r++)
            s_buf[(wv*16 + q*4 + r)*402 + g*16 + n] = f2h(acc[g][r]);
    }
    __syncthreads();

    // ---- Phase D: dw 3x3 from P; thread = (co = t&63, seg = t>>6 -> 16 px) ---
    const int co = t & 63, seg = t >> 6, x0l = seg*16;
    float w9[9];
    {
        const float* wpd = dww + (size_t)(dw_choff + co)*9;
        #pragma unroll
        for (int j=0;j<9;j++) w9[j] = wpd[j];
    }
    float gm[8];
    float qq_own = 0.f, kk_own = 0.f;
    if (MODE == 2){
        #pragma unroll
        for (int d=0;d<8;d++) gm[d] = 0.f;
    }
    const int base = lane & 56;

    #pragma unroll
    for (int yp=0; yp<2; yp++){
        float rwf[4][18];
        #pragma unroll
        for (int wr=0; wr<4; wr++){
            const unsigned* rp = (const unsigned*)&s_buf[co*402 + (yp*2+wr)*66 + x0l];
            #pragma unroll
            for (int j=0;j<9;j++){
                unsigned u = rp[j];
                rwf[wr][2*j]   = h2f((unsigned short)(u & 0xFFFFu));
                rwf[wr][2*j+1] = h2f((unsigned short)(u >> 16));
            }
        }
        #pragma unroll
        for (int yy=0; yy<2; yy++){
            float o[16];
            #pragma unroll
            for (int x=0;x<16;x++){
                float s = 0.f;
                #pragma unroll
                for (int dy=0;dy<3;dy++){
                    #pragma unroll
                    for (int dx=0;dx<3;dx++)
                        s = fmaf(w9[dy*3+dx], rwf[yy+dy][x+dx], s);
                }
                o[x] = s;
            }
            if (MODE == 0 || MODE == 1){
                size_t off = ((size_t)b*64 + co)*HW + (size_t)(y0 + yp*2 + yy)*256 + x0 + x0l;
                #pragma unroll
                for (int j=0;j<4;j++)
                    *(float4*)(outp + off + j*4) = make_float4(o[j*4],o[j*4+1],o[j*4+2],o[j*4+3]);
                if (MODE == 1){
                    #pragma unroll
                    for (int x=0;x<16;x++) kk_own = fmaf(o[x],o[x],kk_own);
                }
            } else {
                #pragma unroll
                for (int x=0;x<16;x++) qq_own = fmaf(o[x],o[x],qq_own);
                const float* kb = kin + ((size_t)b*64 + co)*HW + (size_t)(y0 + yp*2 + yy)*256 + x0 + x0l;
                float4 k4[4];
                #pragma unroll
                for (int j=0;j<4;j++) k4[j] = *(const float4*)(kb + j*4);
                #pragma unroll
                for (int d=0;d<8;d++){
                    #pragma unroll
                    for (int j=0;j<4;j++){
                        float kx = __shfl(k4[j].x, base+d);
                        float ky = __shfl(k4[j].y, base+d);
                        float kz = __shfl(k4[j].z, base+d);
                        float kw = __shfl(k4[j].w, base+d);
                        gm[d] = fmaf(o[j*4+0],kx,gm[d]);
                        gm[d] = fmaf(o[j*4+1],ky,gm[d]);
                        gm[d] = fmaf(o[j*4+2],kz,gm[d]);
                        gm[d] = fmaf(o[j*4+3],kw,gm[d]);
                    }
                }
            }
        }
    }

    if (MODE == 1){
        __syncthreads();                       // P reads done, reuse LDS
        float* redf = (float*)s_buf;
        redf[t] = kk_own;
        __syncthreads();
        if (t < 64){
            float s = redf[t] + redf[64+t] + redf[128+t] + redf[192+t];
            atomicAdd(&kkv[b*64 + t], s);
        }
    }
    if (MODE == 2){
        __syncthreads();
        float* redf = (float*)s_buf;           // [seg][co][9]
        #pragma unroll
        for (int d=0;d<8;d++) redf[seg*576 + co*9 + d] = gm[d];
        redf[seg*576 + co*9 + 8] = qq_own;
        __syncthreads();
        const int blkib = blk & 255;
        for (int i = t; i < 576; i += 256){
            float s = redf[i] + redf[576+i] + redf[1152+i] + redf[1728+i];
            int coi = i / 9, j = i - coi*9;
            if (j < 8) Gp[((size_t)b*576 + coi*8 + j)*256 + blkib] = s;
            else       Gp[((size_t)b*576 + 512 + coi)*256 + blkib] = s;
        }
    }
}

// ======== gram partial reduction: Gp[2304][256] -> G[4][512], qq[4][64] =======
__global__ void gred_kernel(const float* __restrict__ Gp, float* __restrict__ G,
                            float* __restrict__ qq)
{
    int v = blockIdx.x*64 + threadIdx.x;
    if (v >= 2304) return;
    const float4* p = (const float4*)(Gp + (size_t)v*256);
    float s = 0.f;
    for (int j=0;j<64;j++){ float4 f = p[j]; s += f.x+f.y+f.z+f.w; }
    int b = v / 576, i = v - b*576;
    if (i < 512) G[(size_t)b*512 + i] = s;
    else         qq[(size_t)b*64 + (i-512)] = s;
}

// =================== pointwise (1x1) conv via f16 MFMA ========================
template<int CIN, int COTILE>
__global__ __launch_bounds__(256,2)
void pw_mfma_kernel(const float* __restrict__ in, int in_cs, int in_choff,
                    float* __restrict__ out, int out_cs, int out_choff,
                    const unsigned short* __restrict__ wp, int wbstride, int wtot, int co_base,
                    const float* __restrict__ bias,
                    const float* __restrict__ res, int relu_flag, int P)
{
    constexpr int PXT   = (COTILE==32) ? 512 : (COTILE==64 ? 256 : 128);
    constexpr int HCO   = (COTILE==128) ? 2 : 1;
    constexpr int SCNT  = (PXT >= 256) ? 16 : 8;      // px-frags per wave
    constexpr int NHALF = CIN/64;
    constexpr int NLD   = PXT*CIN/1024;               // float4 per thread
    constexpr int PXM   = PXT/4;

    __shared__ __align__(16) unsigned short s_a[NHALF][PXT*72];

    const int t = threadIdx.x;
    const int lane = t & 63, wv = t >> 6;
    const int n = lane & 15, q = lane >> 4;
    const int b = blockIdx.y;
    const int co_b = blockIdx.z * COTILE;
    const int p0 = blockIdx.x * PXT;
    const int colb   = (COTILE==32) ? (wv&1)*16 : wv*16;
    const int pxbase = (COTILE==32) ? (wv>>1)*256 : 0;

    const float* ipb = in + ((size_t)b*in_cs + in_choff)*P + p0;
    {
        float4 tmp[8];
        for (int c0 = 0; c0 < NLD; c0 += 8) {
            #pragma unroll
            for (int i=0;i<8;i++){
                int idx = t + (c0+i)*256;
                int px4 = idx & (PXM-1), ci = idx / PXM;
                tmp[i] = *(const float4*)(ipb + (size_t)ci*P + px4*4);
            }
            #pragma unroll
            for (int i=0;i<8;i++){
                int idx = t + (c0+i)*256;
                int px4 = idx & (PXM-1), ci = idx / PXM;
                unsigned short* d = &s_a[ci>>6][(px4*4)*72 + (ci&63)];
                d[0]   = f2h(tmp[i].x);
                d[72]  = f2h(tmp[i].y);
                d[144] = f2h(tmp[i].z);
                d[216] = f2h(tmp[i].w);
            }
        }
    }
    __syncthreads();

    floatx4 zero = {0.f,0.f,0.f,0.f};
    floatx4 acc[HCO][SCNT];
    #pragma unroll
    for (int h=0;h<HCO;h++)
        #pragma unroll
        for (int s=0;s<SCNT;s++) acc[h][s] = zero;

    f16x8 af[CIN/32][HCO];
    const unsigned short* wpb = wp + (size_t)b*wbstride;
    #pragma unroll
    for (int kk=0;kk<CIN/32;kk++)
        #pragma unroll
        for (int h=0;h<HCO;h++)
            af[kk][h] = *(const f16x8*)&wpb[((size_t)kk*wtot + co_b + h*64 + colb + n)*32 + q*8];

    #pragma unroll
    for (int s=0;s<SCNT;s++){
        #pragma unroll
        for (int kk=0;kk<CIN/32;kk++){
            f16x8 bf = *(const f16x8*)&s_a[kk>>1][(pxbase + s*16 + n)*72 + (kk&1)*32 + q*8];
            #pragma unroll
            for (int h=0;h<HCO;h++)
                acc[h][s] = __builtin_amdgcn_mfma_f32_16x16x32_f16(af[kk][h], bf, acc[h][s], 0,0,0);
        }
    }

    #pragma unroll
    for (int h=0;h<HCO;h++){
        #pragma unroll
        for (int s=0;s<SCNT;s++){
            int px = p0 + pxbase + s*16 + n;
            #pragma unroll
            for (int r=0;r<4;r++){
                int col = h*64 + colb + q*4 + r;     // 0..COTILE-1
                size_t off = ((size_t)b*out_cs + out_choff + col)*P + px;
                float v = acc[h][s][r];
                if (bias) v += bias[col];
                if (relu_flag) v = fmaxf(v, 0.f);
                if (res) v += res[off];
                out[off] = v;
            }
        }
    }
}

// ======================= depthwise 3x3, pad 1, 4 px/thread =====================
__global__ __launch_bounds__(256,4)
void dw3x3_kernel(const float* __restrict__ in, int in_cs, int in_choff,
                  float* __restrict__ out, int out_cs, int out_choff,
                  const float* __restrict__ w, int w_choff,
                  const float* __restrict__ bias)
{
    const int c = blockIdx.x >> 6;
    const int p = ((blockIdx.x & 63) << 10) + threadIdx.x*4;
    const int x = p & 255, y = p >> 8;
    const int b = blockIdx.y;
    const float* ip = in + ((size_t)b*in_cs + in_choff + c)*HW;
    const float* wp = w + (size_t)(w_choff + c)*9;
    float row[3][6];
    #pragma unroll
    for (int dy=0; dy<3; dy++){
        int yy = y + dy - 1;
        if (yy < 0 || yy > 255){
            #pragma unroll
            for (int j=0;j<6;j++) row[dy][j]=0.f;
        } else {
            const float* rp = ip + yy*256;
            float4 m = *(const float4*)(rp + x);
            row[dy][1]=m.x; row[dy][2]=m.y; row[dy][3]=m.z; row[dy][4]=m.w;
            row[dy][0] = (x>0)   ? rp[x-1] : 0.f;
            row[dy][5] = (x<252) ? rp[x+4] : 0.f;
        }
    }
    float bv = bias ? bias[w_choff + c] : 0.f;
    float o[4] = {bv,bv,bv,bv};
    #pragma unroll
    for (int dy=0;dy<3;dy++){
        #pragma unroll
        for (int dx=0;dx<3;dx++){
            float wv = wp[dy*3+dx];
            #pragma unroll
            for (int i=0;i<4;i++) o[i] = fmaf(wv, row[dy][i+dx], o[i]);
        }
    }
    *(float4*)(out + ((size_t)b*out_cs + out_choff + c)*HW + p) =
        make_float4(o[0],o[1],o[2],o[3]);
}

// ======================= FFT kernels ==========================================
__global__ __launch_bounds__(256,4)
void rfftw_kernel(const float* __restrict__ x, float* __restrict__ pm,
                  float* __restrict__ pe)
{
    __shared__ float sre[2*256], sim[2*256];
    const int t = threadIdx.x;
    const int r = t >> 7, lt = t & 127;
    const int row = blockIdx.x*2 + r;
    const int bc = row >> 8, h = row & 255;
    const float* xp = x + (size_t)bc*HW + h*256;
    float* base = sre + r*256; float* basei = sim + r*256;
    {
        int i1 = lt, i2 = lt + 128;
        int r1 = __brev((unsigned)i1) >> 24, r2 = __brev((unsigned)i2) >> 24;
        base[r1] = xp[i1]; basei[r1] = 0.f;
        base[r2] = xp[i2]; basei[r2] = 0.f;
    }
    __syncthreads();
    for (int s=1; s<=8; s++) {
        int m = 1<<s, half = m>>1;
        int j = lt & (half-1);
        int grp = lt >> (s-1);
        int i1 = grp*m + j, i2 = i1 + half;
        float ang = -6.283185307179586f * (float)j / (float)m;
        float sn, cs; __sincosf(ang, &sn, &cs);
        float ar = base[i1], ai = basei[i1];
        float br = base[i2], bi = basei[i2];
        float tr = cs*br - sn*bi, ti = cs*bi + sn*br;
        base[i1] = ar + tr; basei[i1] = ai + ti;
        base[i2] = ar - tr; basei[i2] = ai - ti;
        __syncthreads();
    }
    const int b = bc >> 6, c = bc & 63;
    float* pre = pm + ((size_t)b*128 + c)*32768 + h*128;
    float* pim = pm + ((size_t)b*128 + 64 + c)*32768 + h*128;
    pre[lt] = base[lt]; pim[lt] = basei[lt];
    if (lt == 0) {
        pe[((size_t)b*128 + c)*256 + h]      = base[128];
        pe[((size_t)b*128 + 64 + c)*256 + h] = basei[128];
    }
}

__global__ __launch_bounds__(256,2)
void ffth_kernel(float* __restrict__ pm, float* __restrict__ pe, int inverse)
{
    __shared__ float sre[256*16], sim[256*16];   // [h][col]
    const int t = threadIdx.x;
    const int blk = blockIdx.x;
    const int chunk = blk % 9;
    const int bc = blk / 9;
    const int b = bc >> 6, c = bc & 63;
    const int col = t & 15;
    const int hb = t >> 4;
    const bool edge = (chunk == 8);
    const bool valid = edge ? (col == 0) : true;
    const int k = chunk*16 + col;
    float* pre; float* pim; int hstride;
    if (edge) {
        pre = pe + ((size_t)b*128 + c)*256;
        pim = pe + ((size_t)b*128 + 64 + c)*256;
        hstride = 1;
    } else {
        pre = pm + ((size_t)b*128 + c)*32768 + k;
        pim = pm + ((size_t)b*128 + 64 + c)*32768 + k;
        hstride = 128;
    }
    for (int hh = 0; hh < 16; hh++) {
        int h = hh*16 + hb;
        float vr = 0.f, vi = 0.f;
        if (valid) { vr = pre[h*hstride]; vi = pim[h*hstride]; }
        sre[h*16+col] = vr; sim[h*16+col] = vi;
    }
    __syncthreads();
    if (!inverse) {
        for (int s=8; s>=1; s--) {
            int m = 1<<s, half = m>>1;
            for (int it=0; it<8; it++) {
                int task = it*256 + t;
                int cl = task & 15;
                int bf = task >> 4;
                int j = bf & (half-1);
                int grp = bf >> (s-1);
                int i1 = grp*m + j, i2 = i1 + half;
                float ang = -6.283185307179586f * (float)j / (float)m;
                float sn, cs; __sincosf(ang, &sn, &cs);
                float ar = sre[i1*16+cl], ai = sim[i1*16+cl];
                float br = sre[i2*16+cl], bi = sim[i2*16+cl];
                float dr = ar - br, di = ai - bi;
                sre[i1*16+cl] = ar + br; sim[i1*16+cl] = ai + bi;
                sre[i2*16+cl] = cs*dr - sn*di;
                sim[i2*16+cl] = cs*di + sn*dr;
            }
            __syncthreads();
        }
    } else {
        for (int s=1; s<=8; s++) {
            int m = 1<<s, half = m>>1;
            for (int it=0; it<8; it++) {
                int task = it*256 + t;
                int cl = task & 15;
                int bf = task >> 4;
                int j = bf & (half-1);
                int grp = bf >> (s-1);
                int i1 = grp*m + j, i2 = i1 + half;
                float ang = 6.283185307179586f * (float)j / (float)m;
                float sn, cs; __sincosf(ang, &sn, &cs);
                float ar = sre[i1*16+cl], ai = sim[i1*16+cl];
                float br = sre[i2*16+cl], bi = sim[i2*16+cl];
                float tr = cs*br - sn*bi, ti = cs*bi + sn*br;
                sre[i1*16+cl] = ar + tr; sim[i1*16+cl] = ai + ti;
                sre[i2*16+cl] = ar - tr; sim[i2*16+cl] = ai - ti;
            }
            __syncthreads();
        }
    }
    const float scale = inverse ? (1.0f/256.0f) : 1.0f;
    for (int hh = 0; hh < 16; hh++) {
        int h = hh*16 + hb;
        if (valid) {
            pre[h*hstride] = sre[h*16+col]*scale;
            pim[h*hstride] = sim[h*16+col]*scale;
        }
    }
}

__global__ __launch_bounds__(256,4)
void irfftw_kernel(const float* __restrict__ pm, const float* __restrict__ pe,
                   float* __restrict__ outp)
{
    __shared__ float sre[2*256], sim[2*256];
    const int t = threadIdx.x;
    const int r = t >> 7, lt = t & 127;
    const int row = blockIdx.x*2 + r;
    const int bc = row >> 8, h = row & 255;
    const int b = bc >> 6, c = bc & 63;
    const float* pre = pm + ((size_t)b*128 + c)*32768 + h*128;
    const float* pim = pm + ((size_t)b*128 + 64 + c)*32768 + h*128;
    float* base = sre + r*256; float* basei = sim + r*256;
    {
        float xr = pre[lt], xi = pim[lt];
        int d1 = __brev((unsigned)lt) >> 24;
        base[d1] = xr; basei[d1] = xi;
        int k2 = lt + 128;
        int d2 = __brev((unsigned)k2) >> 24;
        float yr, yi;
        if (lt == 0) {
            yr = pe[((size_t)b*128 + c)*256 + h];
            yi = pe[((size_t)b*128 + 64 + c)*256 + h];
        } else {
            yr = pre[128-lt]; yi = -pim[128-lt];
        }
        base[d2] = yr; basei[d2] = yi;
    }
    __syncthreads();
    for (int s=1; s<=8; s++) {
        int m = 1<<s, half = m>>1;
        int j = lt & (half-1);
        int grp = lt >> (s-1);
        int i1 = grp*m + j, i2 = i1 + half;
        float ang = 6.283185307179586f * (float)j / (float)m;
        float sn, cs; __sincosf(ang, &sn, &cs);
        float ar = base[i1], ai = basei[i1];
        float br = base[i2], bi = basei[i2];
        float tr = cs*br - sn*bi, ti = cs*bi + sn*br;
        base[i1] = ar + tr; basei[i1] = ai + ti;
        base[i2] = ar - tr; basei[i2] = ai - ti;
        __syncthreads();
    }
    float* op = outp + (size_t)bc*HW + h*256;
    op[lt]     = base[lt]     * (1.0f/256.0f);
    op[lt+128] = base[lt+128] * (1.0f/256.0f);
}

// ========= softmax + fold proj into per-batch M (packed f16 for MFMA pw) ======
__global__ void attnmat_kernel(const float* __restrict__ G, const float* __restrict__ qq,
                               const float* __restrict__ kk, const float* __restrict__ temp,
                               const float* __restrict__ projw, unsigned short* __restrict__ Mp)
{
    __shared__ float A[2048];   // [bh][c][d]
    const int t = threadIdx.x;
    for (int i = t; i < 2048; i += 256) {
        int d = i & 7, c = (i>>3)&7, bh = i>>6;
        int h = bh & 7;
        float nq = fmaxf(sqrtf(qq[bh*8+c]), 1e-12f);
        float nk = fmaxf(sqrtf(kk[bh*8+d]), 1e-12f);
        A[i] = G[i] / (nq*nk) * temp[h];
    }
    __syncthreads();
    {
        int base = t*8;
        float mx = -1e30f;
        #pragma unroll
        for (int d=0;d<8;d++) mx = fmaxf(mx, A[base+d]);
        float e[8]; float sum = 0.f;
        #pragma unroll
        for (int d=0;d<8;d++){ e[d] = __expf(A[base+d]-mx); sum += e[d]; }
        float inv = 1.0f/sum;
        #pragma unroll
        for (int d=0;d<8;d++) A[base+d] = e[d]*inv;
    }
    __syncthreads();
    for (int i=t; i<16384; i+=256) {
        int hd = i & 63, co = (i>>6)&63, b = i>>12;
        int h = hd>>3, d = hd&7;
        float s = 0.f;
        #pragma unroll
        for (int c=0;c<8;c++)
            s = fmaf(projw[co*64 + h*8 + c], A[((b*8+h)*8+c)*8 + d], s);
        Mp[(size_t)b*4096 + ((size_t)(hd>>5)*64 + co)*32 + (hd&31)] = f2h(s);
    }
}

// ==== final: pw(64->128) f16 MFMA + bias + sigmoid, gate, nan_to_num ==========
__global__ __launch_bounds__(256,2)
void fuse_final_mfma_kernel(const float* __restrict__ t2, int t2_cs, int t2_choff,
                            const unsigned short* __restrict__ wp,   // [2][128][32] f16
                            const float* __restrict__ bias,
                            const float* __restrict__ fre, const float* __restrict__ spa,
                            float* __restrict__ outp)
{
    __shared__ __align__(16) unsigned short s_a[128*72];
    const int t = threadIdx.x;
    const int lane = t & 63, wv = t >> 6;
    const int n = lane & 15, q = lane >> 4;
    const int b = blockIdx.y;
    const int p0 = blockIdx.x * 128;

    const float* ipb = t2 + ((size_t)b*t2_cs + t2_choff)*HW + p0;
    {
        float4 tmp[8];
        #pragma unroll
        for (int i=0;i<8;i++){
            int idx = t + i*256;
            int px4 = idx & 31, ci = idx >> 5;
            tmp[i] = *(const float4*)(ipb + (size_t)ci*HW + px4*4);
        }
        #pragma unroll
        for (int i=0;i<8;i++){
            int idx = t + i*256;
            int px4 = idx & 31, ci = idx >> 5;
            unsigned short* d = &s_a[(px4*4)*72 + ci];
            d[0]   = f2h(tmp[i].x);
            d[72]  = f2h(tmp[i].y);
            d[144] = f2h(tmp[i].z);
            d[216] = f2h(tmp[i].w);
        }
    }
    __syncthreads();

    floatx4 zero = {0.f,0.f,0.f,0.f};
    floatx4 acc[2][8];
    #pragma unroll
    for (int h=0;h<2;h++)
        #pragma unroll
        for (int s=0;s<8;s++) acc[h][s] = zero;

    f16x8 af[2][2];
    #pragma unroll
    for (int kk=0;kk<2;kk++)
        #pragma unroll
        for (int h=0;h<2;h++)
            af[kk][h] = *(const f16x8*)&wp[((size_t)kk*128 + h*64 + wv*16 + n)*32 + q*8];

    #pragma unroll
    for (int s=0;s<8;s++){
        #pragma unroll
        for (int kk=0;kk<2;kk++){
            f16x8 bf = *(const f16x8*)&s_a[(s*16 + n)*72 + kk*32 + q*8];
            #pragma unroll
            for (int h=0;h<2;h++)
                acc[h][s] = __builtin_amdgcn_mfma_f32_16x16x32_f16(af[kk][h], bf, acc[h][s], 0,0,0);
        }
    }

    #pragma unroll
    for (int s=0;s<8;s++){
        int px = p0 + s*16 + n;
        #pragma unroll
        for (int r=0;r<4;r++){
            int c = wv*16 + q*4 + r;
            float g1 = acc[0][s][r] + bias[c];
            float g2 = acc[1][s][r] + bias[64+c];
            float s1 = 1.0f/(1.0f+__expf(-g1));
            float s2 = 1.0f/(1.0f+__expf(-g2));
            size_t off = ((size_t)b*64 + c)*HW + px;
            float f = fre[off], sp = spa[off];
            float v = f*s1 + s2*sp;
            if (!__builtin_isfinite(v)) v = 1e-5f;
            outp[off] = v;
        }
    }
}

// =============================== launcher =====================================
extern "C" void kernel_launch(void* const* d_in, const int* in_sizes, int n_in,
                              void* d_out, int out_size, void* d_ws, size_t ws_size,
                              hipStream_t stream) {
    const float* x0      = (const float*)d_in[0];
    const float* x1      = (const float*)d_in[1];
    const float* rl_w1   = (const float*)d_in[2];
    const float* rl_b1   = (const float*)d_in[3];
    const float* rl_w2   = (const float*)d_in[4];
    const float* rl_b2   = (const float*)d_in[5];
    const float* rg_w1   = (const float*)d_in[6];
    const float* rg_w2   = (const float*)d_in[7];
    const float* att_temp= (const float*)d_in[8];
    const float* kv_w    = (const float*)d_in[9];
    const float* kv_dw   = (const float*)d_in[10];
    const float* q_w     = (const float*)d_in[11];
    const float* q_dw    = (const float*)d_in[12];
    const float* proj_w  = (const float*)d_in[13];
    const float* f1_dw   = (const float*)d_in[14];
    const float* f1_dwb  = (const float*)d_in[15];
    const float* f1_pw   = (const float*)d_in[16];
    const float* f1_pwb  = (const float*)d_in[17];
    const float* f2_dw   = (const float*)d_in[18];
    const float* f2_dwb  = (const float*)d_in[19];
    const float* f2_pw   = (const float*)d_in[20];
    const float* f2_pwb  = (const float*)d_in[21];
    float* out = (float*)d_out;
    float* ws  = (float*)d_ws;

    const size_t A = (size_t)4*64*HW;       // 16,777,216 floats (64 MB)
    float* R0   = ws;                        // scratch A (freq main / Gp / v)
    float* R1   = ws + A;                    // scratch A (k64)
    float* spa  = ws + 2*A;                  // persistent A
    float* PFe  = ws + 3*A;                  // Nyquist col: 4*128*256 = 131072
    float* PFe2 = PFe + 131072;              // Nyquist scratch
    float* G    = PFe2 + 131072;             // 2048
    float* qqv  = G + 2048;                  // 256
    float* kkv  = qqv + 256;                 // 256
    unsigned short* wbf = (unsigned short*)(kkv + 256);  // conv3x3: 2*36864 u16
    unsigned short* kvP = wbf + 2*36864;     // 2*128*32 = 8192
    unsigned short* qP  = kvP + 8192;        // 2*64*32  = 4096
    unsigned short* rg1P= qP  + 4096;        // 4*128*32 = 16384
    unsigned short* rg2P= rg1P+ 16384;       // 16384
    unsigned short* f1P = rg2P+ 16384;       // 4*64*32  = 8192
    unsigned short* f2P = f1P + 8192;        // 2*128*32 = 8192
    unsigned short* Mp  = f2P + 8192;        // 4*2*64*32 = 16384
    float* fre  = out;                       // fre lives in d_out

    const dim3 dwg64(64*64, 4);

    // ---------- weight prep ----------
    wprep_kernel<<<288,256,0,stream>>>(rl_w1, rl_w2, wbf);
    wpack_kernel<<<32,256,0,stream>>>(kv_w,  kvP, 128, 64);
    wpack_kernel<<<16,256,0,stream>>>(q_w,   qP,   64, 64);
    wpack_kernel<<<64,256,0,stream>>>(rg_w1, rg1P,128,128);
    wpack_kernel<<<64,256,0,stream>>>(rg_w2, rg2P,128,128);
    wpack_kernel<<<32,256,0,stream>>>(f1_pw, f1P,  64,128);
    wpack_kernel<<<32,256,0,stream>>>(f2_pw, f2P, 128, 64);

    // ---------- Stage 1: ResBlock_L -> fre (in d_out) ----------
    conv3x3_mfma_kernel<<<1024,256,0,stream>>>(x0, wbf,         rl_b1, nullptr, R0);
    conv3x3_mfma_kernel<<<1024,256,0,stream>>>(R0, wbf + 36864, rl_b2, x0,      fre);

    // ---------- Stage 2: ResBlock_G -> spa ----------
    rfftw_kernel<<<32768,256,0,stream>>>(x1, R0, PFe);
    ffth_kernel<<<2304,256,0,stream>>>(R0, PFe, 0);
    pw_mfma_kernel<128,128><<<dim3(256,4),256,0,stream>>>(R0,128,0,  R1,128,0,  rg1P,0,128,0, nullptr, nullptr, 1, 32768);
    pw_mfma_kernel<128,128><<<dim3(2,4),  256,0,stream>>>(PFe,128,0, PFe2,128,0, rg1P,0,128,0, nullptr, nullptr, 1, 256);
    pw_mfma_kernel<128,128><<<dim3(256,4),256,0,stream>>>(R1,128,0,  R0,128,0,  rg2P,0,128,0, nullptr, nullptr, 0, 32768);
    pw_mfma_kernel<128,128><<<dim3(2,4),  256,0,stream>>>(PFe2,128,0, PFe,128,0, rg2P,0,128,0, nullptr, nullptr, 0, 256);
    ffth_kernel<<<2304,256,0,stream>>>(R0, PFe, 1);
    irfftw_kernel<<<32768,256,0,stream>>>(R0, PFe, spa);

    // ---------- attention (shared weights), applied twice ----------
    auto attention = [&](const float* xq, const float* ykv, float* io) {
        hipMemsetAsync(G, 0, 2560*sizeof(float), stream);   // G+qq+kk (kk needs 0)
        float* Gp = R0;                                      // 2.36 MB partials in R0
        // k64 = dw(pw(ykv, kv rows 0..63)) -> R1, + kk sums
        pwdw_kernel<1><<<1024,256,0,stream>>>(ykv, kvP, 128, 0,  kv_dw, 0,
                                              R1, nullptr, nullptr, kkv);
        // q (never materialized): gram vs k + qq sums -> Gp
        pwdw_kernel<2><<<1024,256,0,stream>>>(xq,  qP,  64,  0,  q_dw,  0,
                                              nullptr, R1, Gp, nullptr);
        gred_kernel<<<36,64,0,stream>>>(Gp, G, qqv);
        attnmat_kernel<<<1,256,0,stream>>>(G, qqv, kkv, att_temp, proj_w, Mp);
        // v = dw(pw(ykv, kv rows 64..127)) -> R0 (after gred consumed Gp)
        pwdw_kernel<0><<<1024,256,0,stream>>>(ykv, kvP, 128, 64, kv_dw, 64,
                                              R0, nullptr, nullptr, nullptr);
        // io = M_b * v + io   (proj folded into packed M; in-place residual safe)
        pw_mfma_kernel<64,64><<<dim3(256,4),256,0,stream>>>(R0,64,0, io,64,0, Mp,4096,64,0, nullptr, io, 0, HW);
    };
    attention(fre, spa, fre);   // fre = att(fre, spa) + fre
    attention(spa, fre, spa);   // spa = att(spa, fre_new) + spa

    // ---------- Stage 5: fuse (R0..R1 as one [b][128][HW] buffer) -------------
    float* W128 = R0;
    dw3x3_kernel<<<dwg64,256,0,stream>>>(fre,64,0, W128,128,0,  f1_dw, 0,  f1_dwb);
    dw3x3_kernel<<<dwg64,256,0,stream>>>(spa,64,0, W128,128,64, f1_dw, 64, f1_dwb);
    // pw 128->64 +bias, in-place into ch0..63 of W128 (block-local px tiles)
    pw_mfma_kernel<128,64><<<dim3(256,4),256,0,stream>>>(W128,128,0, W128,128,0, f1P,0,64,0, f1_pwb, nullptr, 0, HW);
    // dw3x3 64ch +bias: read ch0..63, write ch64..127 (disjoint)
    dw3x3_kernel<<<dwg64,256,0,stream>>>(W128,128,0, W128,128,64, f2_dw, 0, f2_dwb);
    // pw 64->128 +bias, sigmoid, gate, nan_to_num -> out (in-place with fre)
    fuse_final_mfma_kernel<<<dim3(512,4),256,0,stream>>>(W128,128,64, f2P, f2_pwb, fre, spa, out);
    (void)in_sizes; (void)n_in; (void)out_size; (void)ws_size;
}

// Round 6
// 1162.816 us; speedup vs baseline: 1.7342x; 1.0999x over previous
//
#include <hip/hip_runtime.h>

#define HW 65536            // 256*256

typedef __attribute__((ext_vector_type(8))) _Float16 f16x8;
typedef __attribute__((ext_vector_type(4))) float floatx4;

__device__ inline unsigned short f2h(float f){
    return __builtin_bit_cast(unsigned short, (_Float16)f);
}
__device__ inline float h2f(unsigned short h){
    return (float)__builtin_bit_cast(_Float16, h);
}
// staging swizzle: word index for (flattened px-row p, ci) in stride-72 layout
__device__ inline int swz(int p, int ci){
    return ci ^ (((p>>3)&7)<<3);
}

// ============ merged weight prep: conv3x3 repack + 6 pw packs =================
// conv3x3: OIHW fp32 -> [conv][ch][tap][co][ci32] f16  (2*36864)
// pw packs: [co][ci] fp32 -> [ci/32][co][ci32] f16
__global__ void prep_kernel(const float* __restrict__ w1, const float* __restrict__ w2,
                            const float* __restrict__ kv_w, const float* __restrict__ q_w,
                            const float* __restrict__ rg_w1, const float* __restrict__ rg_w2,
                            const float* __restrict__ f1_pw, const float* __restrict__ f2_pw,
                            unsigned short* __restrict__ wbf, unsigned short* __restrict__ kvP,
                            unsigned short* __restrict__ qP, unsigned short* __restrict__ rg1P,
                            unsigned short* __restrict__ rg2P, unsigned short* __restrict__ f1P,
                            unsigned short* __restrict__ f2P)
{
    int idx = blockIdx.x*256 + threadIdx.x;    // < 135168
    if (idx < 73728) {
        const float* src = (idx < 36864) ? w1 : w2;
        int l = idx % 36864;
        int ch = l / 18432;
        int r  = l % 18432;
        int tap = r >> 11;
        int co  = (r >> 5) & 63;
        int ci  = r & 31;
        wbf[idx] = f2h(src[co*576 + (ch*32+ci)*9 + tap]);
        return;
    }
    int i = idx - 73728;
    const float* src; unsigned short* dst; int CI;
    if (i < 8192)       { src=kv_w;  dst=kvP;  CI=64;  }
    else if (i < 12288) { i-=8192;  src=q_w;   dst=qP;   CI=64;  }
    else if (i < 28672) { i-=12288; src=rg_w1; dst=rg1P; CI=128; }
    else if (i < 45056) { i-=28672; src=rg_w2; dst=rg2P; CI=128; }
    else if (i < 53248) { i-=45056; src=f1_pw; dst=f1P;  CI=128; }
    else                { i-=53248; src=f2_pw; dst=f2P;  CI=64;  }
    int CO = (dst==qP || dst==f1P) ? 64 : 128;
    int ci = i % CI, co = i / CI;
    dst[((size_t)(ci>>5)*CO + co)*32 + (ci&31)] = f2h(src[i]);
}

// ======== dense 3x3 conv 64->64 via f16 MFMA, bias+relu (+res), fp32 io =======
__global__ __launch_bounds__(256,2)
void conv3x3_mfma_kernel(const float* __restrict__ in, const unsigned short* __restrict__ wbf,
                         const float* __restrict__ bias, const float* __restrict__ res,
                         float* __restrict__ out)
{
    __shared__ __align__(16) unsigned short s_in[6*66*72];   // 57024 B
    const int t = threadIdx.x;
    const int lane = t & 63, wv = t >> 6;
    const int n = lane & 15, q = lane >> 4;
    const int blk = blockIdx.x;
    const int xt = blk & 3, yt = (blk>>2) & 63, b = blk >> 8;
    const int x0 = xt*64, y0 = yt*4;

    const float* inb = in + (size_t)b*64*HW;

    // ---- stage 6 rows x 66 cols x 64 ci, fp32 -> f16, [p=row*66+xx][ci^swz] --
    {
        const int xq = t & 15;             // x-group of 4
        const int u0 = t >> 4;             // 0..15, composite ci/row base
        const float* gp0 = inb + x0 + xq*4;
        float4 tmp[12];
        #pragma unroll
        for (int ch = 0; ch < 2; ch++) {
            #pragma unroll
            for (int i = 0; i < 12; i++) {
                int u = u0 + (ch*12 + i)*16;     // 0..383
                int ci = u & 63, row = u >> 6;
                int gy = y0 + row - 1;
                float4 v = make_float4(0.f,0.f,0.f,0.f);
                if (gy >= 0 && gy < 256)
                    v = *(const float4*)(gp0 + (size_t)ci*HW + (size_t)gy*256);
                tmp[i] = v;
            }
            #pragma unroll
            for (int i = 0; i < 12; i++) {
                int u = u0 + (ch*12 + i)*16;
                int ci = u & 63, row = u >> 6;
                int pb = row*66 + xq*4 + 1;
                s_in[(pb+0)*72 + swz(pb+0,ci)] = f2h(tmp[i].x);
                s_in[(pb+1)*72 + swz(pb+1,ci)] = f2h(tmp[i].y);
                s_in[(pb+2)*72 + swz(pb+2,ci)] = f2h(tmp[i].z);
                s_in[(pb+3)*72 + swz(pb+3,ci)] = f2h(tmp[i].w);
            }
        }
        // halo columns
        float hv[3];
        #pragma unroll
        for (int i = 0; i < 3; i++) {
            int idx = i*256 + t;           // < 768
            int ci = idx & 63;
            int side = (idx >> 6) & 1;
            int row = idx >> 7;
            int gx = x0 - 1 + side*65;
            int gy = y0 + row - 1;
            float v = 0.f;
            if (gx >= 0 && gx < 256 && gy >= 0 && gy < 256)
                v = inb[(size_t)ci*HW + (size_t)gy*256 + gx];
            hv[i] = v;
        }
        #pragma unroll
        for (int i = 0; i < 3; i++) {
            int idx = i*256 + t;
            int ci = idx & 63;
            int side = (idx >> 6) & 1;
            int row = idx >> 7;
            int xx = side ? 65 : 0;
            int p = row*66 + xx;
            s_in[p*72 + swz(p,ci)] = f2h(hv[i]);
        }
    }
    __syncthreads();

    floatx4 zero = {0.f,0.f,0.f,0.f};
    floatx4 acc[4][4];
    #pragma unroll
    for (int y=0;y<4;y++)
        #pragma unroll
        for (int s=0;s<4;s++) acc[y][s] = zero;

    for (int kk = 0; kk < 2; kk++) {
        f16x8 af[9];
        #pragma unroll
        for (int tap=0; tap<9; tap++)
            af[tap] = *(const f16x8*)&wbf[kk*18432 + tap*2048 + (wv*16 + n)*32 + q*8];
        #pragma unroll
        for (int s=0;s<4;s++){
            #pragma unroll
            for (int dx=0;dx<3;dx++){
                f16x8 bf[6];
                #pragma unroll
                for (int r6=0;r6<6;r6++){
                    int p = r6*66 + s*16 + n + dx;
                    bf[r6] = *(const f16x8*)&s_in[p*72 + ((((kk<<2)|q) ^ ((p>>3)&7))<<3)];
                }
                #pragma unroll
                for (int dy=0;dy<3;dy++){
                    #pragma unroll
                    for (int y=0;y<4;y++)
                        acc[y][s] = __builtin_amdgcn_mfma_f32_16x16x32_f16(
                            af[dy*3+dx], bf[y+dy], acc[y][s], 0,0,0);
                }
            }
        }
    }

    #pragma unroll
    for (int y=0;y<4;y++){
        #pragma unroll
        for (int s=0;s<4;s++){
            #pragma unroll
            for (int r=0;r<4;r++){
                int co = wv*16 + q*4 + r;
                int px = x0 + s*16 + n;
                size_t off = ((size_t)b*64+co)*HW + (size_t)(y0+y)*256 + px;
                float v = fmaxf(acc[y][s][r] + bias[co], 0.f);
                if (res) v += res[off];
                out[off] = v;
            }
        }
    }
}

// ============ fused pw(1x1,64->64 f16 MFMA) + dw(3x3) for attention ===========
// Tile: 64px x 4 rows x 64 co.  Grid: 4 xt * 64 yt * 4 b = 1024 blocks.
// MODE 1: store dw output (k) + kk sums.
// MODE 2: no store; gram vs kin via wave shuffles, partials -> Gp (q).
// MODE 3: v path: dw output -> LDS, MFMA with Mp (M·v), += residual io.
template<int MODE>
__global__ __launch_bounds__(256,2)
void pwdw_kernel(const float* __restrict__ in,
                 const unsigned short* __restrict__ wp, int wtot, int co_base,
                 const float* __restrict__ dww, int dw_choff,
                 float* __restrict__ outp,
                 const float* __restrict__ kin,
                 float* __restrict__ Gp,
                 float* __restrict__ kkv,
                 const unsigned short* __restrict__ mw)
{
    __shared__ __align__(16) unsigned short s_buf[400*72];   // 57600 B
    const int t = threadIdx.x;
    const int lane = t & 63, wv = t >> 6;
    const int n = lane & 15, q = lane >> 4;
    const int blk = blockIdx.x;
    const int xt = blk & 3, yt = (blk>>2) & 63, b = blk >> 8;
    const int x0 = xt*64, y0 = yt*4;
    const float* inb = in + (size_t)b*64*HW;

    // ---- Phase A: stage 6x66x64 fp32->f16, [p][ci^swz] stride 72 ----
    {
        const int xq = t & 15;
        const int u0 = t >> 4;
        const float* gp0 = inb + x0 + xq*4;
        float4 tmp[12];
        #pragma unroll
        for (int ch = 0; ch < 2; ch++) {
            #pragma unroll
            for (int i = 0; i < 12; i++) {
                int u = u0 + (ch*12 + i)*16;
                int ci = u & 63, row = u >> 6;
                int gy = y0 + row - 1;
                float4 v = make_float4(0.f,0.f,0.f,0.f);
                if (gy >= 0 && gy < 256)
                    v = *(const float4*)(gp0 + (size_t)ci*HW + (size_t)gy*256);
                tmp[i] = v;
            }
            #pragma unroll
            for (int i = 0; i < 12; i++) {
                int u = u0 + (ch*12 + i)*16;
                int ci = u & 63, row = u >> 6;
                int pb = row*66 + xq*4 + 1;
                s_buf[(pb+0)*72 + swz(pb+0,ci)] = f2h(tmp[i].x);
                s_buf[(pb+1)*72 + swz(pb+1,ci)] = f2h(tmp[i].y);
                s_buf[(pb+2)*72 + swz(pb+2,ci)] = f2h(tmp[i].z);
                s_buf[(pb+3)*72 + swz(pb+3,ci)] = f2h(tmp[i].w);
            }
        }
        float hv[3];
        #pragma unroll
        for (int i = 0; i < 3; i++) {
            int idx = i*256 + t;
            int ci = idx & 63;
            int side = (idx >> 6) & 1;
            int row = idx >> 7;
            int gx = x0 - 1 + side*65;
            int gy = y0 + row - 1;
            float v = 0.f;
            if (gx >= 0 && gx < 256 && gy >= 0 && gy < 256)
                v = inb[(size_t)ci*HW + (size_t)gy*256 + gx];
            hv[i] = v;
        }
        #pragma unroll
        for (int i = 0; i < 3; i++) {
            int idx = i*256 + t;
            int ci = idx & 63;
            int side = (idx >> 6) & 1;
            int row = idx >> 7;
            int xx = side ? 65 : 0;
            int p = row*66 + xx;
            s_buf[p*72 + swz(p,ci)] = f2h(hv[i]);
        }
    }
    __syncthreads();

    // ---- Phase B: pw MFMA over 25 px-groups ----
    floatx4 zero = {0.f,0.f,0.f,0.f};
    floatx4 acc[25];
    #pragma unroll
    for (int g=0;g<25;g++) acc[g] = zero;
    f16x8 af[2];
    #pragma unroll
    for (int kk=0;kk<2;kk++)
        af[kk] = *(const f16x8*)&wp[((size_t)(kk*wtot + co_base + wv*16 + n))*32 + q*8];
    #pragma unroll
    for (int g=0;g<25;g++){
        int p = g*16 + n;
        #pragma unroll
        for (int kk=0;kk<2;kk++){
            f16x8 bf = *(const f16x8*)&s_buf[p*72 + ((((kk<<2)|q) ^ ((p>>3)&7))<<3)];
            acc[g] = __builtin_amdgcn_mfma_f32_16x16x32_f16(af[kk], bf, acc[g], 0,0,0);
        }
    }
    __syncthreads();   // all staging reads done before P overwrite

    // ---- Phase C: P[co][402] f16 (bank-stride 201 -> conflict-free reads) ----
    #pragma unroll
    for (int g=0;g<25;g++){
        #pragma unroll
        for (int r=0;r<4;r++)
            s_buf[(wv*16 + q*4 + r)*402 + g*16 + n] = f2h(acc[g][r]);
    }
    __syncthreads();

    // ---- Phase D: dw 3x3 from P; thread = (co = t&63, seg = t>>6 -> 16 px) ---
    const int co = t & 63, seg = t >> 6, x0l = seg*16;
    float w9[9];
    {
        const float* wpd = dww + (size_t)(dw_choff + co)*9;
        #pragma unroll
        for (int j=0;j<9;j++) w9[j] = wpd[j];
    }

    if constexpr (MODE == 3) {
        // compute all 4 rows into regs
        float o4[4][16];
        #pragma unroll
        for (int yp=0; yp<2; yp++){
            float rwf[4][18];
            #pragma unroll
            for (int wr=0; wr<4; wr++){
                const unsigned* rp = (const unsigned*)&s_buf[co*402 + (yp*2+wr)*66 + x0l];
                #pragma unroll
                for (int j=0;j<9;j++){
                    unsigned u = rp[j];
                    rwf[wr][2*j]   = h2f((unsigned short)(u & 0xFFFFu));
                    rwf[wr][2*j+1] = h2f((unsigned short)(u >> 16));
                }
            }
            #pragma unroll
            for (int yy=0; yy<2; yy++){
                #pragma unroll
                for (int x=0;x<16;x++){
                    float s = 0.f;
                    #pragma unroll
                    for (int dy=0;dy<3;dy++)
                        #pragma unroll
                        for (int dx=0;dx<3;dx++)
                            s = fmaf(w9[dy*3+dx], rwf[yy+dy][x+dx], s);
                    o4[yp*2+yy][x] = s;
                }
            }
        }
        __syncthreads();          // all P reads done
        // write v -> LDS [pxl][ci=co] stride 72 swizzled
        #pragma unroll
        for (int r4=0;r4<4;r4++){
            #pragma unroll
            for (int j=0;j<16;j++){
                int pxl = r4*64 + x0l + j;
                s_buf[pxl*72 + swz(pxl,co)] = f2h(o4[r4][j]);
            }
        }
        __syncthreads();
        // MFMA: out[co2][pxl] = sum_ci M[co2][ci] * v[ci][pxl]
        f16x8 am[2];
        #pragma unroll
        for (int kk=0;kk<2;kk++)
            am[kk] = *(const f16x8*)&mw[(size_t)b*4096 + ((size_t)kk*64 + wv*16 + n)*32 + q*8];
        floatx4 accm[16];
        #pragma unroll
        for (int s=0;s<16;s++) accm[s] = zero;
        #pragma unroll
        for (int s=0;s<16;s++){
            int p = s*16 + n;
            #pragma unroll
            for (int kk=0;kk<2;kk++){
                f16x8 bf = *(const f16x8*)&s_buf[p*72 + ((((kk<<2)|q) ^ ((p>>3)&7))<<3)];
                accm[s] = __builtin_amdgcn_mfma_f32_16x16x32_f16(am[kk], bf, accm[s], 0,0,0);
            }
        }
        #pragma unroll
        for (int s=0;s<16;s++){
            int pxl = s*16 + n;
            int yy = pxl >> 6, xx = pxl & 63;
            #pragma unroll
            for (int r=0;r<4;r++){
                int coo = wv*16 + q*4 + r;
                size_t off = ((size_t)b*64+coo)*HW + (size_t)(y0+yy)*256 + x0 + xx;
                outp[off] = accm[s][r] + outp[off];   // += residual io
            }
        }
        return;
    }

    float gm[8];
    float qq_own = 0.f, kk_own = 0.f;
    if (MODE == 2){
        #pragma unroll
        for (int d=0;d<8;d++) gm[d] = 0.f;
    }
    const int base = lane & 56;

    #pragma unroll
    for (int yp=0; yp<2; yp++){
        float rwf[4][18];
        #pragma unroll
        for (int wr=0; wr<4; wr++){
            const unsigned* rp = (const unsigned*)&s_buf[co*402 + (yp*2+wr)*66 + x0l];
            #pragma unroll
            for (int j=0;j<9;j++){
                unsigned u = rp[j];
                rwf[wr][2*j]   = h2f((unsigned short)(u & 0xFFFFu));
                rwf[wr][2*j+1] = h2f((unsigned short)(u >> 16));
            }
        }
        #pragma unroll
        for (int yy=0; yy<2; yy++){
            float o[16];
            #pragma unroll
            for (int x=0;x<16;x++){
                float s = 0.f;
                #pragma unroll
                for (int dy=0;dy<3;dy++){
                    #pragma unroll
                    for (int dx=0;dx<3;dx++)
                        s = fmaf(w9[dy*3+dx], rwf[yy+dy][x+dx], s);
                }
                o[x] = s;
            }
            if (MODE == 1){
                size_t off = ((size_t)b*64 + co)*HW + (size_t)(y0 + yp*2 + yy)*256 + x0 + x0l;
                #pragma unroll
                for (int j=0;j<4;j++)
                    *(float4*)(outp + off + j*4) = make_float4(o[j*4],o[j*4+1],o[j*4+2],o[j*4+3]);
                #pragma unroll
                for (int x=0;x<16;x++) kk_own = fmaf(o[x],o[x],kk_own);
            } else {
                #pragma unroll
                for (int x=0;x<16;x++) qq_own = fmaf(o[x],o[x],qq_own);
                const float* kb = kin + ((size_t)b*64 + co)*HW + (size_t)(y0 + yp*2 + yy)*256 + x0 + x0l;
                float4 k4[4];
                #pragma unroll
                for (int j=0;j<4;j++) k4[j] = *(const float4*)(kb + j*4);
                #pragma unroll
                for (int d=0;d<8;d++){
                    #pragma unroll
                    for (int j=0;j<4;j++){
                        float kx = __shfl(k4[j].x, base+d);
                        float ky = __shfl(k4[j].y, base+d);
                        float kz = __shfl(k4[j].z, base+d);
                        float kw = __shfl(k4[j].w, base+d);
                        gm[d] = fmaf(o[j*4+0],kx,gm[d]);
                        gm[d] = fmaf(o[j*4+1],ky,gm[d]);
                        gm[d] = fmaf(o[j*4+2],kz,gm[d]);
                        gm[d] = fmaf(o[j*4+3],kw,gm[d]);
                    }
                }
            }
        }
    }

    if (MODE == 1){
        __syncthreads();                       // P reads done, reuse LDS
        float* redf = (float*)s_buf;
        redf[t] = kk_own;
        __syncthreads();
        if (t < 64){
            float s = redf[t] + redf[64+t] + redf[128+t] + redf[192+t];
            atomicAdd(&kkv[b*64 + t], s);
        }
    }
    if (MODE == 2){
        __syncthreads();
        float* redf = (float*)s_buf;           // [seg][co][9]
        #pragma unroll
        for (int d=0;d<8;d++) redf[seg*576 + co*9 + d] = gm[d];
        redf[seg*576 + co*9 + 8] = qq_own;
        __syncthreads();
        const int blkib = blk & 255;
        for (int i = t; i < 576; i += 256){
            float s = redf[i] + redf[576+i] + redf[1152+i] + redf[1728+i];
            int coi = i / 9, j = i - coi*9;
            if (j < 8) Gp[((size_t)b*576 + coi*8 + j)*256 + blkib] = s;
            else       Gp[((size_t)b*576 + 512 + coi)*256 + blkib] = s;
        }
    }
}

// ======== gram partial reduction: Gp[2304][256] -> G[4][512], qq[4][64] =======
__global__ void gred_kernel(const float* __restrict__ Gp, float* __restrict__ G,
                            float* __restrict__ qq)
{
    int v = blockIdx.x*64 + threadIdx.x;
    if (v >= 2304) return;
    const float4* p = (const float4*)(Gp + (size_t)v*256);
    float s = 0.f;
    for (int j=0;j<64;j++){ float4 f = p[j]; s += f.x+f.y+f.z+f.w; }
    int b = v / 576, i = v - b*576;
    if (i < 512) G[(size_t)b*512 + i] = s;
    else         qq[(size_t)b*64 + (i-512)] = s;
}

// =================== pointwise (1x1) conv via f16 MFMA ========================
template<int CIN, int COTILE>
__global__ __launch_bounds__(256,2)
void pw_mfma_kernel(const float* __restrict__ in, int in_cs, int in_choff,
                    float* __restrict__ out, int out_cs, int out_choff,
                    const unsigned short* __restrict__ wp, int wbstride, int wtot, int co_base,
                    const float* __restrict__ bias,
                    const float* __restrict__ res, int relu_flag, int P)
{
    constexpr int PXT   = (COTILE==32) ? 512 : (COTILE==64 ? 256 : 128);
    constexpr int HCO   = (COTILE==128) ? 2 : 1;
    constexpr int SCNT  = (PXT >= 256) ? 16 : 8;      // px-frags per wave
    constexpr int NHALF = CIN/64;
    constexpr int NLD   = PXT*CIN/1024;               // float4 per thread
    constexpr int PXM   = PXT/4;

    __shared__ __align__(16) unsigned short s_a[NHALF][PXT*72];

    const int t = threadIdx.x;
    const int lane = t & 63, wv = t >> 6;
    const int n = lane & 15, q = lane >> 4;
    const int b = blockIdx.y;
    const int co_b = blockIdx.z * COTILE;
    const int p0 = blockIdx.x * PXT;
    const int colb   = (COTILE==32) ? (wv&1)*16 : wv*16;
    const int pxbase = (COTILE==32) ? (wv>>1)*256 : 0;

    const float* ipb = in + ((size_t)b*in_cs + in_choff)*P + p0;
    {
        float4 tmp[8];
        for (int c0 = 0; c0 < NLD; c0 += 8) {
            #pragma unroll
            for (int i=0;i<8;i++){
                int idx = t + (c0+i)*256;
                int px4 = idx & (PXM-1), ci = idx / PXM;
                tmp[i] = *(const float4*)(ipb + (size_t)ci*P + px4*4);
            }
            #pragma unroll
            for (int i=0;i<8;i++){
                int idx = t + (c0+i)*256;
                int px4 = idx & (PXM-1), ci = idx / PXM;
                int cih = ci & 63, half = ci >> 6;
                int pb = px4*4;
                s_a[half][(pb+0)*72 + swz(pb+0,cih)] = f2h(tmp[i].x);
                s_a[half][(pb+1)*72 + swz(pb+1,cih)] = f2h(tmp[i].y);
                s_a[half][(pb+2)*72 + swz(pb+2,cih)] = f2h(tmp[i].z);
                s_a[half][(pb+3)*72 + swz(pb+3,cih)] = f2h(tmp[i].w);
            }
        }
    }
    __syncthreads();

    floatx4 zero = {0.f,0.f,0.f,0.f};
    floatx4 acc[HCO][SCNT];
    #pragma unroll
    for (int h=0;h<HCO;h++)
        #pragma unroll
        for (int s=0;s<SCNT;s++) acc[h][s] = zero;

    f16x8 af[CIN/32][HCO];
    const unsigned short* wpb = wp + (size_t)b*wbstride;
    #pragma unroll
    for (int kk=0;kk<CIN/32;kk++)
        #pragma unroll
        for (int h=0;h<HCO;h++)
            af[kk][h] = *(const f16x8*)&wpb[((size_t)kk*wtot + co_b + h*64 + colb + n)*32 + q*8];

    #pragma unroll
    for (int s=0;s<SCNT;s++){
        int p = pxbase + s*16 + n;
        #pragma unroll
        for (int kk=0;kk<CIN/32;kk++){
            f16x8 bf = *(const f16x8*)&s_a[kk>>1][p*72 + (((((kk&1)<<2)|q) ^ ((p>>3)&7))<<3)];
            #pragma unroll
            for (int h=0;h<HCO;h++)
                acc[h][s] = __builtin_amdgcn_mfma_f32_16x16x32_f16(af[kk][h], bf, acc[h][s], 0,0,0);
        }
    }

    #pragma unroll
    for (int h=0;h<HCO;h++){
        #pragma unroll
        for (int s=0;s<SCNT;s++){
            int px = p0 + pxbase + s*16 + n;
            #pragma unroll
            for (int r=0;r<4;r++){
                int col = h*64 + colb + q*4 + r;     // 0..COTILE-1
                size_t off = ((size_t)b*out_cs + out_choff + col)*P + px;
                float v = acc[h][s][r];
                if (bias) v += bias[col];
                if (relu_flag) v = fmaxf(v, 0.f);
                if (res) v += res[off];
                out[off] = v;
            }
        }
    }
}

// ======================= depthwise 3x3, pad 1, 4 px/thread =====================
__global__ __launch_bounds__(256,4)
void dw3x3_kernel(const float* __restrict__ in, int in_cs, int in_choff,
                  float* __restrict__ out, int out_cs, int out_choff,
                  const float* __restrict__ w, int w_choff,
                  const float* __restrict__ bias)
{
    const int c = blockIdx.x >> 6;
    const int p = ((blockIdx.x & 63) << 10) + threadIdx.x*4;
    const int x = p & 255, y = p >> 8;
    const int b = blockIdx.y;
    const float* ip = in + ((size_t)b*in_cs + in_choff + c)*HW;
    const float* wp = w + (size_t)(w_choff + c)*9;
    float row[3][6];
    #pragma unroll
    for (int dy=0; dy<3; dy++){
        int yy = y + dy - 1;
        if (yy < 0 || yy > 255){
            #pragma unroll
            for (int j=0;j<6;j++) row[dy][j]=0.f;
        } else {
            const float* rp = ip + yy*256;
            float4 m = *(const float4*)(rp + x);
            row[dy][1]=m.x; row[dy][2]=m.y; row[dy][3]=m.z; row[dy][4]=m.w;
            row[dy][0] = (x>0)   ? rp[x-1] : 0.f;
            row[dy][5] = (x<252) ? rp[x+4] : 0.f;
        }
    }
    float bv = bias ? bias[w_choff + c] : 0.f;
    float o[4] = {bv,bv,bv,bv};
    #pragma unroll
    for (int dy=0;dy<3;dy++){
        #pragma unroll
        for (int dx=0;dx<3;dx++){
            float wv = wp[dy*3+dx];
            #pragma unroll
            for (int i=0;i<4;i++) o[i] = fmaf(wv, row[dy][i+dx], o[i]);
        }
    }
    *(float4*)(out + ((size_t)b*out_cs + out_choff + c)*HW + p) =
        make_float4(o[0],o[1],o[2],o[3]);
}

// ======================= FFT kernels ==========================================
__global__ __launch_bounds__(256,4)
void rfftw_kernel(const float* __restrict__ x, float* __restrict__ pm,
                  float* __restrict__ pe)
{
    __shared__ float sre[2*256], sim[2*256];
    const int t = threadIdx.x;
    const int r = t >> 7, lt = t & 127;
    const int row = blockIdx.x*2 + r;
    const int bc = row >> 8, h = row & 255;
    const float* xp = x + (size_t)bc*HW + h*256;
    float* base = sre + r*256; float* basei = sim + r*256;
    {
        int i1 = lt, i2 = lt + 128;
        int r1 = __brev((unsigned)i1) >> 24, r2 = __brev((unsigned)i2) >> 24;
        base[r1] = xp[i1]; basei[r1] = 0.f;
        base[r2] = xp[i2]; basei[r2] = 0.f;
    }
    __syncthreads();
    for (int s=1; s<=8; s++) {
        int m = 1<<s, half = m>>1;
        int j = lt & (half-1);
        int grp = lt >> (s-1);
        int i1 = grp*m + j, i2 = i1 + half;
        float ang = -6.283185307179586f * (float)j / (float)m;
        float sn, cs; __sincosf(ang, &sn, &cs);
        float ar = base[i1], ai = basei[i1];
        float br = base[i2], bi = basei[i2];
        float tr = cs*br - sn*bi, ti = cs*bi + sn*br;
        base[i1] = ar + tr; basei[i1] = ai + ti;
        base[i2] = ar - tr; basei[i2] = ai - ti;
        __syncthreads();
    }
    const int b = bc >> 6, c = bc & 63;
    float* pre = pm + ((size_t)b*128 + c)*32768 + h*128;
    float* pim = pm + ((size_t)b*128 + 64 + c)*32768 + h*128;
    pre[lt] = base[lt]; pim[lt] = basei[lt];
    if (lt == 0) {
        pe[((size_t)b*128 + c)*256 + h]      = base[128];
        pe[((size_t)b*128 + 64 + c)*256 + h] = basei[128];
    }
}

__global__ __launch_bounds__(256,2)
void ffth_kernel(float* __restrict__ pm, float* __restrict__ pe, int inverse)
{
    __shared__ float sre[256*16], sim[256*16];   // [h][col]
    const int t = threadIdx.x;
    const int blk = blockIdx.x;
    const int chunk = blk % 9;
    const int bc = blk / 9;
    const int b = bc >> 6, c = bc & 63;
    const int col = t & 15;
    const int hb = t >> 4;
    const bool edge = (chunk == 8);
    const bool valid = edge ? (col == 0) : true;
    const int k = chunk*16 + col;
    float* pre; float* pim; int hstride;
    if (edge) {
        pre = pe + ((size_t)b*128 + c)*256;
        pim = pe + ((size_t)b*128 + 64 + c)*256;
        hstride = 1;
    } else {
        pre = pm + ((size_t)b*128 + c)*32768 + k;
        pim = pm + ((size_t)b*128 + 64 + c)*32768 + k;
        hstride = 128;
    }
    for (int hh = 0; hh < 16; hh++) {
        int h = hh*16 + hb;
        float vr = 0.f, vi = 0.f;
        if (valid) { vr = pre[h*hstride]; vi = pim[h*hstride]; }
        sre[h*16+col] = vr; sim[h*16+col] = vi;
    }
    __syncthreads();
    if (!inverse) {
        for (int s=8; s>=1; s--) {
            int m = 1<<s, half = m>>1;
            for (int it=0; it<8; it++) {
                int task = it*256 + t;
                int cl = task & 15;
                int bf = task >> 4;
                int j = bf & (half-1);
                int grp = bf >> (s-1);
                int i1 = grp*m + j, i2 = i1 + half;
                float ang = -6.283185307179586f * (float)j / (float)m;
                float sn, cs; __sincosf(ang, &sn, &cs);
                float ar = sre[i1*16+cl], ai = sim[i1*16+cl];
                float br = sre[i2*16+cl], bi = sim[i2*16+cl];
                float dr = ar - br, di = ai - bi;
                sre[i1*16+cl] = ar + br; sim[i1*16+cl] = ai + bi;
                sre[i2*16+cl] = cs*dr - sn*di;
                sim[i2*16+cl] = cs*di + sn*dr;
            }
            __syncthreads();
        }
    } else {
        for (int s=1; s<=8; s++) {
            int m = 1<<s, half = m>>1;
            for (int it=0; it<8; it++) {
                int task = it*256 + t;
                int cl = task & 15;
                int bf = task >> 4;
                int j = bf & (half-1);
                int grp = bf >> (s-1);
                int i1 = grp*m + j, i2 = i1 + half;
                float ang = 6.283185307179586f * (float)j / (float)m;
                float sn, cs; __sincosf(ang, &sn, &cs);
                float ar = sre[i1*16+cl], ai = sim[i1*16+cl];
                float br = sre[i2*16+cl], bi = sim[i2*16+cl];
                float tr = cs*br - sn*bi, ti = cs*bi + sn*br;
                sre[i1*16+cl] = ar + tr; sim[i1*16+cl] = ai + ti;
                sre[i2*16+cl] = ar - tr; sim[i2*16+cl] = ai - ti;
            }
            __syncthreads();
        }
    }
    const float scale = inverse ? (1.0f/256.0f) : 1.0f;
    for (int hh = 0; hh < 16; hh++) {
        int h = hh*16 + hb;
        if (valid) {
            pre[h*hstride] = sre[h*16+col]*scale;
            pim[h*hstride] = sim[h*16+col]*scale;
        }
    }
}

__global__ __launch_bounds__(256,4)
void irfftw_kernel(const float* __restrict__ pm, const float* __restrict__ pe,
                   float* __restrict__ outp)
{
    __shared__ float sre[2*256], sim[2*256];
    const int t = threadIdx.x;
    const int r = t >> 7, lt = t & 127;
    const int row = blockIdx.x*2 + r;
    const int bc = row >> 8, h = row & 255;
    const int b = bc >> 6, c = bc & 63;
    const float* pre = pm + ((size_t)b*128 + c)*32768 + h*128;
    const float* pim = pm + ((size_t)b*128 + 64 + c)*32768 + h*128;
    float* base = sre + r*256; float* basei = sim + r*256;
    {
        float xr = pre[lt], xi = pim[lt];
        int d1 = __brev((unsigned)lt) >> 24;
        base[d1] = xr; basei[d1] = xi;
        int k2 = lt + 128;
        int d2 = __brev((unsigned)k2) >> 24;
        float yr, yi;
        if (lt == 0) {
            yr = pe[((size_t)b*128 + c)*256 + h];
            yi = pe[((size_t)b*128 + 64 + c)*256 + h];
        } else {
            yr = pre[128-lt]; yi = -pim[128-lt];
        }
        base[d2] = yr; basei[d2] = yi;
    }
    __syncthreads();
    for (int s=1; s<=8; s++) {
        int m = 1<<s, half = m>>1;
        int j = lt & (half-1);
        int grp = lt >> (s-1);
        int i1 = grp*m + j, i2 = i1 + half;
        float ang = 6.283185307179586f * (float)j / (float)m;
        float sn, cs; __sincosf(ang, &sn, &cs);
        float ar = base[i1], ai = basei[i1];
        float br = base[i2], bi = basei[i2];
        float tr = cs*br - sn*bi, ti = cs*bi + sn*br;
        base[i1] = ar + tr; basei[i1] = ai + ti;
        base[i2] = ar - tr; basei[i2] = ai - ti;
        __syncthreads();
    }
    float* op = outp + (size_t)bc*HW + h*256;
    op[lt]     = base[lt]     * (1.0f/256.0f);
    op[lt+128] = base[lt+128] * (1.0f/256.0f);
}

// ========= softmax + fold proj into per-batch M (packed f16 for MFMA pw) ======
__global__ void attnmat_kernel(const float* __restrict__ G, const float* __restrict__ qq,
                               const float* __restrict__ kk, const float* __restrict__ temp,
                               const float* __restrict__ projw, unsigned short* __restrict__ Mp)
{
    __shared__ float A[2048];   // [bh][c][d]
    const int t = threadIdx.x;
    for (int i = t; i < 2048; i += 256) {
        int d = i & 7, c = (i>>3)&7, bh = i>>6;
        int h = bh & 7;
        float nq = fmaxf(sqrtf(qq[bh*8+c]), 1e-12f);
        float nk = fmaxf(sqrtf(kk[bh*8+d]), 1e-12f);
        A[i] = G[i] / (nq*nk) * temp[h];
    }
    __syncthreads();
    {
        int base = t*8;
        float mx = -1e30f;
        #pragma unroll
        for (int d=0;d<8;d++) mx = fmaxf(mx, A[base+d]);
        float e[8]; float sum = 0.f;
        #pragma unroll
        for (int d=0;d<8;d++){ e[d] = __expf(A[base+d]-mx); sum += e[d]; }
        float inv = 1.0f/sum;
        #pragma unroll
        for (int d=0;d<8;d++) A[base+d] = e[d]*inv;
    }
    __syncthreads();
    for (int i=t; i<16384; i+=256) {
        int hd = i & 63, co = (i>>6)&63, b = i>>12;
        int h = hd>>3, d = hd&7;
        float s = 0.f;
        #pragma unroll
        for (int c=0;c<8;c++)
            s = fmaf(projw[co*64 + h*8 + c], A[((b*8+h)*8+c)*8 + d], s);
        Mp[(size_t)b*4096 + ((size_t)(hd>>5)*64 + co)*32 + (hd&31)] = f2h(s);
    }
}

// ==== final: pw(64->128) f16 MFMA + bias + sigmoid, gate, nan_to_num ==========
__global__ __launch_bounds__(256,2)
void fuse_final_mfma_kernel(const float* __restrict__ t2, int t2_cs, int t2_choff,
                            const unsigned short* __restrict__ wp,   // [2][128][32] f16
                            const float* __restrict__ bias,
                            const float* __restrict__ fre, const float* __restrict__ spa,
                            float* __restrict__ outp)
{
    __shared__ __align__(16) unsigned short s_a[128*72];
    const int t = threadIdx.x;
    const int lane = t & 63, wv = t >> 6;
    const int n = lane & 15, q = lane >> 4;
    const int b = blockIdx.y;
    const int p0 = blockIdx.x * 128;

    const float* ipb = t2 + ((size_t)b*t2_cs + t2_choff)*HW + p0;
    {
        float4 tmp[8];
        #pragma unroll
        for (int i=0;i<8;i++){
            int idx = t + i*256;
            int px4 = idx & 31, ci = idx >> 5;
            tmp[i] = *(const float4*)(ipb + (size_t)ci*HW + px4*4);
        }
        #pragma unroll
        for (int i=0;i<8;i++){
            int idx = t + i*256;
            int px4 = idx & 31, ci = idx >> 5;
            int pb = px4*4;
            s_a[(pb+0)*72 + swz(pb+0,ci)] = f2h(tmp[i].x);
            s_a[(pb+1)*72 + swz(pb+1,ci)] = f2h(tmp[i].y);
            s_a[(pb+2)*72 + swz(pb+2,ci)] = f2h(tmp[i].z);
            s_a[(pb+3)*72 + swz(pb+3,ci)] = f2h(tmp[i].w);
        }
    }
    __syncthreads();

    floatx4 zero = {0.f,0.f,0.f,0.f};
    floatx4 acc[2][8];
    #pragma unroll
    for (int h=0;h<2;h++)
        #pragma unroll
        for (int s=0;s<8;s++) acc[h][s] = zero;

    f16x8 af[2][2];
    #pragma unroll
    for (int kk=0;kk<2;kk++)
        #pragma unroll
        for (int h=0;h<2;h++)
            af[kk][h] = *(const f16x8*)&wp[((size_t)kk*128 + h*64 + wv*16 + n)*32 + q*8];

    #pragma unroll
    for (int s=0;s<8;s++){
        int p = s*16 + n;
        #pragma unroll
        for (int kk=0;kk<2;kk++){
            f16x8 bf = *(const f16x8*)&s_a[p*72 + ((((kk<<2)|q) ^ ((p>>3)&7))<<3)];
            #pragma unroll
            for (int h=0;h<2;h++)
                acc[h][s] = __builtin_amdgcn_mfma_f32_16x16x32_f16(af[kk][h], bf, acc[h][s], 0,0,0);
        }
    }

    #pragma unroll
    for (int s=0;s<8;s++){
        int px = p0 + s*16 + n;
        #pragma unroll
        for (int r=0;r<4;r++){
            int c = wv*16 + q*4 + r;
            float g1 = acc[0][s][r] + bias[c];
            float g2 = acc[1][s][r] + bias[64+c];
            float s1 = 1.0f/(1.0f+__expf(-g1));
            float s2 = 1.0f/(1.0f+__expf(-g2));
            size_t off = ((size_t)b*64 + c)*HW + px;
            float f = fre[off], sp = spa[off];
            float v = f*s1 + s2*sp;
            if (!__builtin_isfinite(v)) v = 1e-5f;
            outp[off] = v;
        }
    }
}

// =============================== launcher =====================================
extern "C" void kernel_launch(void* const* d_in, const int* in_sizes, int n_in,
                              void* d_out, int out_size, void* d_ws, size_t ws_size,
                              hipStream_t stream) {
    const float* x0      = (const float*)d_in[0];
    const float* x1      = (const float*)d_in[1];
    const float* rl_w1   = (const float*)d_in[2];
    const float* rl_b1   = (const float*)d_in[3];
    const float* rl_w2   = (const float*)d_in[4];
    const float* rl_b2   = (const float*)d_in[5];
    const float* rg_w1   = (const float*)d_in[6];
    const float* rg_w2   = (const float*)d_in[7];
    const float* att_temp= (const float*)d_in[8];
    const float* kv_w    = (const float*)d_in[9];
    const float* kv_dw   = (const float*)d_in[10];
    const float* q_w     = (const float*)d_in[11];
    const float* q_dw    = (const float*)d_in[12];
    const float* proj_w  = (const float*)d_in[13];
    const float* f1_dw   = (const float*)d_in[14];
    const float* f1_dwb  = (const float*)d_in[15];
    const float* f1_pw   = (const float*)d_in[16];
    const float* f1_pwb  = (const float*)d_in[17];
    const float* f2_dw   = (const float*)d_in[18];
    const float* f2_dwb  = (const float*)d_in[19];
    const float* f2_pw   = (const float*)d_in[20];
    const float* f2_pwb  = (const float*)d_in[21];
    float* out = (float*)d_out;
    float* ws  = (float*)d_ws;

    const size_t A = (size_t)4*64*HW;       // 16,777,216 floats (64 MB)
    float* R0   = ws;                        // scratch A (freq main / Gp)
    float* R1   = ws + A;                    // scratch A (k64)
    float* spa  = ws + 2*A;                  // persistent A
    float* PFe  = ws + 3*A;                  // Nyquist col: 4*128*256 = 131072
    float* PFe2 = PFe + 131072;              // Nyquist scratch
    float* G    = PFe2 + 131072;             // 2048
    float* qqv  = G + 2048;                  // 256
    float* kkv  = qqv + 256;                 // 256
    unsigned short* wbf = (unsigned short*)(kkv + 256);  // conv3x3: 2*36864 u16
    unsigned short* kvP = wbf + 2*36864;     // 2*128*32 = 8192
    unsigned short* qP  = kvP + 8192;        // 2*64*32  = 4096
    unsigned short* rg1P= qP  + 4096;        // 4*128*32 = 16384
    unsigned short* rg2P= rg1P+ 16384;       // 16384
    unsigned short* f1P = rg2P+ 16384;       // 4*64*32  = 8192
    unsigned short* f2P = f1P + 8192;        // 2*128*32 = 8192
    unsigned short* Mp  = f2P + 8192;        // 4*2*64*32 = 16384
    float* fre  = out;                       // fre lives in d_out

    const dim3 dwg64(64*64, 4);

    // ---------- weight prep (one launch) ----------
    prep_kernel<<<528,256,0,stream>>>(rl_w1, rl_w2, kv_w, q_w, rg_w1, rg_w2,
                                      f1_pw, f2_pw,
                                      wbf, kvP, qP, rg1P, rg2P, f1P, f2P);

    // ---------- Stage 1: ResBlock_L -> fre (in d_out) ----------
    conv3x3_mfma_kernel<<<1024,256,0,stream>>>(x0, wbf,         rl_b1, nullptr, R0);
    conv3x3_mfma_kernel<<<1024,256,0,stream>>>(R0, wbf + 36864, rl_b2, x0,      fre);

    // ---------- Stage 2: ResBlock_G -> spa ----------
    rfftw_kernel<<<32768,256,0,stream>>>(x1, R0, PFe);
    ffth_kernel<<<2304,256,0,stream>>>(R0, PFe, 0);
    pw_mfma_kernel<128,128><<<dim3(256,4),256,0,stream>>>(R0,128,0,  R1,128,0,  rg1P,0,128,0, nullptr, nullptr, 1, 32768);
    pw_mfma_kernel<128,128><<<dim3(2,4),  256,0,stream>>>(PFe,128,0, PFe2,128,0, rg1P,0,128,0, nullptr, nullptr, 1, 256);
    pw_mfma_kernel<128,128><<<dim3(256,4),256,0,stream>>>(R1,128,0,  R0,128,0,  rg2P,0,128,0, nullptr, nullptr, 0, 32768);
    pw_mfma_kernel<128,128><<<dim3(2,4),  256,0,stream>>>(PFe2,128,0, PFe,128,0, rg2P,0,128,0, nullptr, nullptr, 0, 256);
    ffth_kernel<<<2304,256,0,stream>>>(R0, PFe, 1);
    irfftw_kernel<<<32768,256,0,stream>>>(R0, PFe, spa);

    // ---------- attention (shared weights), applied twice ----------
    auto attention = [&](const float* xq, const float* ykv, float* io) {
        hipMemsetAsync(G, 0, 2560*sizeof(float), stream);   // G+qq+kk (kk needs 0)
        float* Gp = R0;                                      // 2.36 MB partials in R0
        // k64 = dw(pw(ykv, kv rows 0..63)) -> R1, + kk sums
        pwdw_kernel<1><<<1024,256,0,stream>>>(ykv, kvP, 128, 0,  kv_dw, 0,
                                              R1, nullptr, nullptr, kkv, nullptr);
        // q (never materialized): gram vs k + qq sums -> Gp
        pwdw_kernel<2><<<1024,256,0,stream>>>(xq,  qP,  64,  0,  q_dw,  0,
                                              nullptr, R1, Gp, nullptr, nullptr);
        gred_kernel<<<36,64,0,stream>>>(Gp, G, qqv);
        attnmat_kernel<<<1,256,0,stream>>>(G, qqv, kkv, att_temp, proj_w, Mp);
        // v = dw(pw(ykv, kv rows 64..127)); io += M_b * v  (fused, in-LDS v)
        pwdw_kernel<3><<<1024,256,0,stream>>>(ykv, kvP, 128, 64, kv_dw, 64,
                                              io, nullptr, nullptr, nullptr, Mp);
    };
    attention(fre, spa, fre);   // fre = att(fre, spa) + fre
    attention(spa, fre, spa);   // spa = att(spa, fre_new) + spa

    // ---------- Stage 5: fuse (R0..R1 as one [b][128][HW] buffer) -------------
    float* W128 = R0;
    dw3x3_kernel<<<dwg64,256,0,stream>>>(fre,64,0, W128,128,0,  f1_dw, 0,  f1_dwb);
    dw3x3_kernel<<<dwg64,256,0,stream>>>(spa,64,0, W128,128,64, f1_dw, 64, f1_dwb);
    // pw 128->64 +bias, in-place into ch0..63 of W128 (block-local px tiles)
    pw_mfma_kernel<128,64><<<dim3(256,4),256,0,stream>>>(W128,128,0, W128,128,0, f1P,0,64,0, f1_pwb, nullptr, 0, HW);
    // dw3x3 64ch +bias: read ch0..63, write ch64..127 (disjoint)
    dw3x3_kernel<<<dwg64,256,0,stream>>>(W128,128,0, W128,128,64, f2_dw, 0, f2_dwb);
    // pw 64->128 +bias, sigmoid, gate, nan_to_num -> out (in-place with fre)
    fuse_final_mfma_kernel<<<dim3(512,4),256,0,stream>>>(W128,128,64, f2P, f2_pwb, fre, spa, out);
    (void)in_sizes; (void)n_in; (void)out_size; (void)ws_size;
}